// Round 1
// baseline (486.547 us; speedup 1.0000x reference)
//
#include <hip/hip_runtime.h>
#include <hip/hip_bf16.h>

#define N_NODES 100000
#define N_EDGES 3200000
#define NBKT 391      // ceil(N_NODES/256): bucket = dst>>8
#define BKT_CAP 10240 // avg 8184 edges/bucket, +23 sigma margin

typedef __hip_bfloat16 bf16;
typedef unsigned int uint;
typedef __attribute__((ext_vector_type(8))) short bf16x8;
typedef __attribute__((ext_vector_type(4))) float f32x4;

__device__ __forceinline__ float b2f(bf16 v) { return __bfloat162float(v); }

__device__ __forceinline__ float bits2f(unsigned short w) {
    union { unsigned short u; bf16 b; } c;
    c.u = w;
    return __bfloat162float(c.b);
}
__device__ __forceinline__ unsigned short f2bits(float f) {  // truncate
    return (unsigned short)(__float_as_uint(f) >> 16);
}
__device__ __forceinline__ unsigned short f2bf_bits(float f) {  // RNE
    bf16 b = __float2bfloat16(f);
    unsigned short u;
    __builtin_memcpy(&u, &b, 2);
    return u;
}

// runtime dtype accessors -------------------------------------------------
__device__ __forceinline__ int get_idx(const void* ei, long long pos, int is64) {
    if (is64) return (int)((const long long*)ei)[pos];
    return ((const int*)ei)[pos];
}
__device__ __forceinline__ float get_f(const void* p, long long pos, int isbf) {
    if (isbf) return b2f(((const bf16*)p)[pos]);
    return ((const float*)p)[pos];
}

// ---------------- dtype detection (1 wave) ----------------
__global__ void detect_kernel(const void* __restrict__ x,
                              const void* __restrict__ ei,
                              int* __restrict__ flags) {
    int lane = threadIdx.x;  // 64 threads
    const unsigned short* xw = (const unsigned short*)x;
    float v = bits2f(xw[2 * lane]);
    bool plaus = (v == v) && fabsf(v) > 1e-3f && fabsf(v) < 1e2f;
    unsigned long long m1 = __ballot(plaus);
    const int* iw = (const int*)ei;
    bool z = (iw[2 * lane + 1] == 0);
    unsigned long long m2 = __ballot(z);
    if (lane == 0) {
        flags[0] = (__popcll(m1) >= 32) ? 1 : 0;
        flags[1] = (__popcll(m2) == 64) ? 1 : 0;
    }
}

// ---------------- pass A: bucket edges by dst>>8 ----------------
__global__ __launch_bounds__(256) void scatterA_kernel(
    const void* __restrict__ ei, int* __restrict__ bucket_cursor,
    uint* __restrict__ bucket_data, const int* __restrict__ flags) {
    __shared__ int lhist[NBKT];
    __shared__ int lbase[NBKT];
    int is64 = flags[1];
    int t = threadIdx.x;
    int chunk0 = blockIdx.x * 8192;
    int dreg[32];

    for (int i = t; i < NBKT; i += 256) lhist[i] = 0;
    __syncthreads();
#pragma unroll
    for (int j = 0; j < 32; j++) {
        int e = chunk0 + j * 256 + t;
        int d = -1;
        if (e < N_EDGES) {
            d = get_idx(ei, (long long)N_EDGES + e, is64);
            atomicAdd(&lhist[d >> 8], 1);
        }
        dreg[j] = d;
    }
    __syncthreads();
    for (int i = t; i < NBKT; i += 256) {
        int c = lhist[i];
        lbase[i] = c ? atomicAdd(&bucket_cursor[i], c) : 0;
        lhist[i] = 0;  // reuse as local cursor
    }
    __syncthreads();
#pragma unroll
    for (int j = 0; j < 32; j++) {
        int e = chunk0 + j * 256 + t;
        int d = dreg[j];
        if (d >= 0) {
            int s = get_idx(ei, e, is64);
            int b = d >> 8;
            int o = lbase[b] + atomicAdd(&lhist[b], 1);
            if (o < BKT_CAP)
                bucket_data[(long long)b * BKT_CAP + o] = ((uint)(d & 255) << 17) | (uint)s;
        }
    }
}

// ---------------- scan bucket counts -> bucket base ----------------
__global__ void scanBuckets_kernel(const int* __restrict__ cnt,
                                   int* __restrict__ base) {
    __shared__ int buf[512];
    int t = threadIdx.x;  // 512 threads
    int v = (t < NBKT) ? cnt[t] : 0;
    buf[t] = v;
    __syncthreads();
    for (int off = 1; off < 512; off <<= 1) {
        int add = (t >= off) ? buf[t - off] : 0;
        __syncthreads();
        buf[t] += add;
        __syncthreads();
    }
    if (t < NBKT) base[t] = buf[t] - v;  // exclusive
}

// ---------------- pass B: per-bucket CSR build ----------------
__global__ __launch_bounds__(256) void csrB_kernel(
    const int* __restrict__ bucket_cnt, const int* __restrict__ bucket_base,
    const uint* __restrict__ bucket_data, int* __restrict__ csr_src,
    int* __restrict__ row_start) {
    __shared__ int lh[256];
    __shared__ int buf[256];
    int b = blockIdx.x;
    int t = threadIdx.x;
    int cnt = bucket_cnt[b];
    if (cnt > BKT_CAP) cnt = BKT_CAP;
    int base = bucket_base[b];
    const uint* bd = bucket_data + (long long)b * BKT_CAP;

    lh[t] = 0;
    __syncthreads();
    for (int i = t; i < cnt; i += 256) atomicAdd(&lh[bd[i] >> 17], 1);
    __syncthreads();
    int v = lh[t];
    buf[t] = v;
    __syncthreads();
    for (int off = 1; off < 256; off <<= 1) {
        int add = (t >= off) ? buf[t - off] : 0;
        __syncthreads();
        buf[t] += add;
        __syncthreads();
    }
    int excl = buf[t] - v;
    int g = (b << 8) + t;
    if (g < N_NODES) row_start[g] = base + excl;
    lh[t] = excl;  // reuse as local cursor
    __syncthreads();
    for (int i = t; i < cnt; i += 256) {
        uint e = bd[i];
        int o = atomicAdd(&lh[e >> 17], 1);
        csr_src[base + o] = (int)(e & 0x1FFFFu);
    }
    if (b == 0 && t == 0) row_start[N_NODES] = N_EDGES;
}

// unpack-accumulate helpers ----------------------------------------------
#define ACC8(acc, v, v2)                                                         \
    acc[0] += __uint_as_float((v).x << 16) + __uint_as_float((v2).x << 16);       \
    acc[1] += __uint_as_float((v).x & 0xffff0000u) + __uint_as_float((v2).x & 0xffff0000u); \
    acc[2] += __uint_as_float((v).y << 16) + __uint_as_float((v2).y << 16);       \
    acc[3] += __uint_as_float((v).y & 0xffff0000u) + __uint_as_float((v2).y & 0xffff0000u); \
    acc[4] += __uint_as_float((v).z << 16) + __uint_as_float((v2).z << 16);       \
    acc[5] += __uint_as_float((v).z & 0xffff0000u) + __uint_as_float((v2).z & 0xffff0000u); \
    acc[6] += __uint_as_float((v).w << 16) + __uint_as_float((v2).w << 16);       \
    acc[7] += __uint_as_float((v).w & 0xffff0000u) + __uint_as_float((v2).w & 0xffff0000u);

#define ACCF4(acc, v, v2)                                                        \
    acc[0] += __uint_as_float((v).x) + __uint_as_float((v2).x);                   \
    acc[1] += __uint_as_float((v).y) + __uint_as_float((v2).y);                   \
    acc[2] += __uint_as_float((v).z) + __uint_as_float((v2).z);                   \
    acc[3] += __uint_as_float((v).w) + __uint_as_float((v2).w);

// ---------------- layer-1 gather: channel-sliced, XCD-L2-resident ----------------
// 4 channel slices of 16 ch (bf16 slice = 3.2 MB < 4 MiB per-XCD L2).
// cz = (blockIdx%8)>>1 pins each slice to a pair of XCDs (round-robin bid%8->XCD).
// Each pass writes a disjoint 16-channel stripe of aggbuf -> no cross-pass races.
__global__ __launch_bounds__(256) void gather1_kernel(
    const void* __restrict__ x, const int* __restrict__ row_start,
    const int* __restrict__ csr_src, bf16* __restrict__ aggbuf,
    const int* __restrict__ flags) {
    int isbf = flags[0];
    int t = threadIdx.x;
    int lane = t & 63;
    int w = t >> 6;
    int bid = blockIdx.x;
    int cz = (bid & 7) >> 1;                                  // channel slice 0..3
    int wid = ((((bid >> 3) << 1) | (bid & 1)) << 2) + w;     // wave id within cz
    int nw = gridDim.x;                                       // waves per cz
    const uint4* x4 = (const uint4*)x;

    if (isbf) {
        // bf16 row = 8 uint4; slice = 2 uint4 chunks. 32 edge slots x 2 chunks.
        int e32 = lane >> 1, q2 = lane & 1;
        int cbase = cz * 2 + q2;
        for (int quad = wid; quad < N_NODES / 4; quad += nw) {
            int nb0 = quad * 4;
            int r0 = row_start[nb0], r1 = row_start[nb0 + 1],
                r2 = row_start[nb0 + 2], r3 = row_start[nb0 + 3],
                r4 = row_start[nb0 + 4];
            int d0 = r1 - r0, d1 = r2 - r1, d2 = r3 - r2, d3 = r4 - r3;
            int maxd = max(max(d0, d1), max(d2, d3));
            float a0[8] = {0,0,0,0,0,0,0,0}, a1[8] = {0,0,0,0,0,0,0,0};
            float a2[8] = {0,0,0,0,0,0,0,0}, a3[8] = {0,0,0,0,0,0,0,0};
            for (int off = 0; off < maxd; off += 64) {
                int iA = r0 + off + e32, iA2 = iA + 32;
                int iB = r1 + off + e32, iB2 = iB + 32;
                int iC = r2 + off + e32, iC2 = iC + 32;
                int iD = r3 + off + e32, iD2 = iD + 32;
                int sA  = (iA  < r1) ? csr_src[iA]  : -1;
                int sA2 = (iA2 < r1) ? csr_src[iA2] : -1;
                int sB  = (iB  < r2) ? csr_src[iB]  : -1;
                int sB2 = (iB2 < r2) ? csr_src[iB2] : -1;
                int sC  = (iC  < r3) ? csr_src[iC]  : -1;
                int sC2 = (iC2 < r3) ? csr_src[iC2] : -1;
                int sD  = (iD  < r4) ? csr_src[iD]  : -1;
                int sD2 = (iD2 < r4) ? csr_src[iD2] : -1;
                uint4 vA = {0,0,0,0}, vA2 = {0,0,0,0}, vB = {0,0,0,0}, vB2 = {0,0,0,0};
                uint4 vC = {0,0,0,0}, vC2 = {0,0,0,0}, vD = {0,0,0,0}, vD2 = {0,0,0,0};
                if (sA  >= 0) vA  = x4[sA  * 8 + cbase];
                if (sA2 >= 0) vA2 = x4[sA2 * 8 + cbase];
                if (sB  >= 0) vB  = x4[sB  * 8 + cbase];
                if (sB2 >= 0) vB2 = x4[sB2 * 8 + cbase];
                if (sC  >= 0) vC  = x4[sC  * 8 + cbase];
                if (sC2 >= 0) vC2 = x4[sC2 * 8 + cbase];
                if (sD  >= 0) vD  = x4[sD  * 8 + cbase];
                if (sD2 >= 0) vD2 = x4[sD2 * 8 + cbase];
                ACC8(a0, vA, vA2)
                ACC8(a1, vB, vB2)
                ACC8(a2, vC, vC2)
                ACC8(a3, vD, vD2)
            }
#pragma unroll
            for (int m = 2; m <= 32; m <<= 1)
#pragma unroll
                for (int k = 0; k < 8; k++) {
                    a0[k] += __shfl_xor(a0[k], m, 64);
                    a1[k] += __shfl_xor(a1[k], m, 64);
                    a2[k] += __shfl_xor(a2[k], m, 64);
                    a3[k] += __shfl_xor(a3[k], m, 64);
                }
            // lane l: node nl = l>>4, slice-channel c = l&15, k = c&7, src lane = c>>3
            int c = lane & 15, nl = lane >> 4;
            int srcq = (lane >> 3) & 1;
            float v0 = 0, v1 = 0, v2 = 0, v3 = 0;
#pragma unroll
            for (int k = 0; k < 8; k++) {
                float t0 = __shfl(a0[k], srcq, 64);
                float t1 = __shfl(a1[k], srcq, 64);
                float t2 = __shfl(a2[k], srcq, 64);
                float t3 = __shfl(a3[k], srcq, 64);
                bool sel = (lane & 7) == k;
                v0 = sel ? t0 : v0;
                v1 = sel ? t1 : v1;
                v2 = sel ? t2 : v2;
                v3 = sel ? t3 : v3;
            }
            float val = (nl == 0) ? v0 : (nl == 1) ? v1 : (nl == 2) ? v2 : v3;
            int dd = (nl == 0) ? d0 : (nl == 1) ? d1 : (nl == 2) ? d2 : d3;
            val *= 1.0f / fmaxf((float)dd, 1.0f);
            aggbuf[(long long)(nb0 + nl) * 64 + cz * 16 + c] = __float2bfloat16(val);
        }
    } else {
        // fp32 row = 16 uint4; slice = 4 uint4 chunks. 16 edge slots x 4 chunks.
        int e16 = lane >> 2, q4 = lane & 3;
        int cbase = cz * 4 + q4;
        for (int quad = wid; quad < N_NODES / 4; quad += nw) {
            int nb0 = quad * 4;
            int r0 = row_start[nb0], r1 = row_start[nb0 + 1],
                r2 = row_start[nb0 + 2], r3 = row_start[nb0 + 3],
                r4 = row_start[nb0 + 4];
            int d0 = r1 - r0, d1 = r2 - r1, d2 = r3 - r2, d3 = r4 - r3;
            int maxd = max(max(d0, d1), max(d2, d3));
            float a0[4] = {0,0,0,0}, a1[4] = {0,0,0,0};
            float a2[4] = {0,0,0,0}, a3[4] = {0,0,0,0};
            for (int off = 0; off < maxd; off += 32) {
                int iA = r0 + off + e16, iA2 = iA + 16;
                int iB = r1 + off + e16, iB2 = iB + 16;
                int iC = r2 + off + e16, iC2 = iC + 16;
                int iD = r3 + off + e16, iD2 = iD + 16;
                int sA  = (iA  < r1) ? csr_src[iA]  : -1;
                int sA2 = (iA2 < r1) ? csr_src[iA2] : -1;
                int sB  = (iB  < r2) ? csr_src[iB]  : -1;
                int sB2 = (iB2 < r2) ? csr_src[iB2] : -1;
                int sC  = (iC  < r3) ? csr_src[iC]  : -1;
                int sC2 = (iC2 < r3) ? csr_src[iC2] : -1;
                int sD  = (iD  < r4) ? csr_src[iD]  : -1;
                int sD2 = (iD2 < r4) ? csr_src[iD2] : -1;
                uint4 vA = {0,0,0,0}, vA2 = {0,0,0,0}, vB = {0,0,0,0}, vB2 = {0,0,0,0};
                uint4 vC = {0,0,0,0}, vC2 = {0,0,0,0}, vD = {0,0,0,0}, vD2 = {0,0,0,0};
                if (sA  >= 0) vA  = x4[sA  * 16 + cbase];
                if (sA2 >= 0) vA2 = x4[sA2 * 16 + cbase];
                if (sB  >= 0) vB  = x4[sB  * 16 + cbase];
                if (sB2 >= 0) vB2 = x4[sB2 * 16 + cbase];
                if (sC  >= 0) vC  = x4[sC  * 16 + cbase];
                if (sC2 >= 0) vC2 = x4[sC2 * 16 + cbase];
                if (sD  >= 0) vD  = x4[sD  * 16 + cbase];
                if (sD2 >= 0) vD2 = x4[sD2 * 16 + cbase];
                ACCF4(a0, vA, vA2)
                ACCF4(a1, vB, vB2)
                ACCF4(a2, vC, vC2)
                ACCF4(a3, vD, vD2)
            }
#pragma unroll
            for (int m = 4; m <= 32; m <<= 1)
#pragma unroll
                for (int k = 0; k < 4; k++) {
                    a0[k] += __shfl_xor(a0[k], m, 64);
                    a1[k] += __shfl_xor(a1[k], m, 64);
                    a2[k] += __shfl_xor(a2[k], m, 64);
                    a3[k] += __shfl_xor(a3[k], m, 64);
                }
            int c = lane & 15, nl = lane >> 4;
            int srcq = (lane >> 2) & 3;  // = c>>2
            float v0 = 0, v1 = 0, v2 = 0, v3 = 0;
#pragma unroll
            for (int k = 0; k < 4; k++) {
                float t0 = __shfl(a0[k], srcq, 64);
                float t1 = __shfl(a1[k], srcq, 64);
                float t2 = __shfl(a2[k], srcq, 64);
                float t3 = __shfl(a3[k], srcq, 64);
                bool sel = (lane & 3) == k;
                v0 = sel ? t0 : v0;
                v1 = sel ? t1 : v1;
                v2 = sel ? t2 : v2;
                v3 = sel ? t3 : v3;
            }
            float val = (nl == 0) ? v0 : (nl == 1) ? v1 : (nl == 2) ? v2 : v3;
            int dd = (nl == 0) ? d0 : (nl == 1) ? d1 : (nl == 2) ? d2 : d3;
            val *= 1.0f / fmaxf((float)dd, 1.0f);
            aggbuf[(long long)(nb0 + nl) * 64 + cz * 16 + c] = __float2bfloat16(val);
        }
    }
}

// ---------------- layer-1+2 GEMMs (MFMA, dense coalesced staging) ----------------
__global__ __launch_bounds__(256) void gemm1_kernel(
    const void* __restrict__ x, const bf16* __restrict__ aggbuf,
    const void* __restrict__ W1l, const void* __restrict__ b1l,
    const void* __restrict__ W1r, const void* __restrict__ W2l,
    const void* __restrict__ b2l, const void* __restrict__ W2r,
    bf16* __restrict__ zbuf, bf16* __restrict__ rbuf,
    const int* __restrict__ flags) {
    __shared__ __align__(16) unsigned short sW1t[64][136];
    __shared__ __align__(16) unsigned short sA[64][136];
    __shared__ __align__(16) unsigned short sW2t[64][72];
    __shared__ __align__(16) unsigned short sH[64][72];
    __shared__ float sB1[64];
    __shared__ float sB2[32];

    int isbf = flags[0];
    int t = threadIdx.x;
    int n0 = blockIdx.x * 64;

    for (int i = t; i < 64 * 128; i += 256) {
        int n = i & 63, k = i >> 6;
        unsigned short v;
        if (isbf)
            v = (k < 64) ? ((const unsigned short*)W1l)[k * 64 + n]
                         : ((const unsigned short*)W1r)[(k - 64) * 64 + n];
        else
            v = f2bits((k < 64) ? ((const float*)W1l)[k * 64 + n]
                                : ((const float*)W1r)[(k - 64) * 64 + n]);
        sW1t[n][k] = v;
    }
    for (int i = t; i < 64 * 64; i += 256) {
        int n = i & 63, k = i >> 6;
        unsigned short v;
        if (isbf)
            v = (n < 32) ? ((const unsigned short*)W2l)[k * 32 + n]
                         : ((const unsigned short*)W2r)[k * 32 + (n - 32)];
        else
            v = f2bits((n < 32) ? ((const float*)W2l)[k * 32 + n]
                                : ((const float*)W2r)[k * 32 + (n - 32)]);
        sW2t[n][k] = v;
    }
    if (t < 64) sB1[t] = get_f(b1l, t, isbf);
    if (t < 32) sB2[t] = get_f(b2l, t, isbf);

    const uint4* ag4 = (const uint4*)aggbuf;
    if (isbf) {
        const uint4* x4 = (const uint4*)x;
        for (int i = t; i < 64 * 16; i += 256) {
            int m = i >> 4, c = i & 15;
            int nn = min(n0 + m, N_NODES - 1);
            uint4 v = (c < 8) ? ag4[(long long)nn * 8 + c]
                              : x4[(long long)nn * 8 + (c - 8)];
            *(uint4*)&sA[m][c * 8] = v;
        }
    } else {
        for (int i = t; i < 64 * 8; i += 256) {
            int m = i >> 3, c = i & 7;
            int nn = min(n0 + m, N_NODES - 1);
            *(uint4*)&sA[m][c * 8] = ag4[(long long)nn * 8 + c];
        }
        const float* xf = (const float*)x;
        for (int i = t; i < 64 * 64; i += 256) {
            int m = i >> 6, c = i & 63;
            int nn = min(n0 + m, N_NODES - 1);
            sA[m][64 + c] = f2bf_bits(xf[(long long)nn * 64 + c]);
        }
    }
    __syncthreads();

    int w = t >> 6, lane = t & 63;
    int mbase = w * 16;
    int q = lane >> 4, r15 = lane & 15;
    f32x4 acc1[4] = {{0,0,0,0},{0,0,0,0},{0,0,0,0},{0,0,0,0}};
#pragma unroll
    for (int ks = 0; ks < 4; ks++) {
        bf16x8 afrag = *(const bf16x8*)&sA[mbase + r15][ks * 32 + q * 8];
#pragma unroll
        for (int nt = 0; nt < 4; nt++) {
            bf16x8 bfrag = *(const bf16x8*)&sW1t[nt * 16 + r15][ks * 32 + q * 8];
            acc1[nt] = __builtin_amdgcn_mfma_f32_16x16x32_bf16(afrag, bfrag, acc1[nt], 0, 0, 0);
        }
    }
#pragma unroll
    for (int nt = 0; nt < 4; nt++) {
        int col = nt * 16 + r15;
        float bias = sB1[col];
#pragma unroll
        for (int rr = 0; rr < 4; rr++) {
            int m = mbase + q * 4 + rr;
            sH[m][col] = f2bf_bits(fmaxf(acc1[nt][rr] + bias, 0.0f));
        }
    }
    __syncthreads();

    f32x4 acc2[4] = {{0,0,0,0},{0,0,0,0},{0,0,0,0},{0,0,0,0}};
#pragma unroll
    for (int ks = 0; ks < 2; ks++) {
        bf16x8 afrag = *(const bf16x8*)&sH[mbase + r15][ks * 32 + q * 8];
#pragma unroll
        for (int nt = 0; nt < 4; nt++) {
            bf16x8 bfrag = *(const bf16x8*)&sW2t[nt * 16 + r15][ks * 32 + q * 8];
            acc2[nt] = __builtin_amdgcn_mfma_f32_16x16x32_bf16(afrag, bfrag, acc2[nt], 0, 0, 0);
        }
    }
#pragma unroll
    for (int nt = 0; nt < 4; nt++) {
        int col = nt * 16 + r15;
#pragma unroll
        for (int rr = 0; rr < 4; rr++) {
            int m = mbase + q * 4 + rr;
            int n = n0 + m;
            if (n < N_NODES) {
                float v = acc2[nt][rr];
                if (col < 32)
                    zbuf[(long long)n * 32 + col] = __float2bfloat16(v);
                else
                    rbuf[(long long)n * 32 + (col - 32)] = __float2bfloat16(v + sB2[col - 32]);
            }
        }
    }
}

// ---------------- layer-2: gather z, channel-sliced (2 slices of 16 ch) ----------------
// z slice = 3.2 MB < 4 MiB per-XCD L2; cz = (bid%8)>>2 pins slice to 4 XCDs.
__global__ __launch_bounds__(256) void node2_kernel(
    const int* __restrict__ row_start, const int* __restrict__ csr_src,
    const bf16* __restrict__ z, const bf16* __restrict__ rbuf,
    void* __restrict__ out, const int* __restrict__ flags) {
    int isbf = flags[0];
    int t = threadIdx.x;
    int lane = t & 63;
    int w = t >> 6;
    int bid = blockIdx.x;
    int cz = (bid & 7) >> 2;                                   // slice 0..1
    int wid = ((((bid >> 3) << 2) | (bid & 3)) << 2) + w;      // wave id within cz
    int nw = gridDim.x * 2;                                    // waves per cz
    const uint4* zr = (const uint4*)z;                         // z row = 4 uint4

    int e32 = lane >> 1, q2 = lane & 1;
    int cbase = cz * 2 + q2;
    for (int quad = wid; quad < N_NODES / 4; quad += nw) {
        int nb0 = quad * 4;
        int r0 = row_start[nb0], r1 = row_start[nb0 + 1],
            r2 = row_start[nb0 + 2], r3 = row_start[nb0 + 3],
            r4 = row_start[nb0 + 4];
        int d0 = r1 - r0, d1 = r2 - r1, d2 = r3 - r2, d3 = r4 - r3;
        int maxd = max(max(d0, d1), max(d2, d3));
        float a0[8] = {0,0,0,0,0,0,0,0}, a1[8] = {0,0,0,0,0,0,0,0};
        float a2[8] = {0,0,0,0,0,0,0,0}, a3[8] = {0,0,0,0,0,0,0,0};
        for (int off = 0; off < maxd; off += 64) {
            int iA = r0 + off + e32, iA2 = iA + 32;
            int iB = r1 + off + e32, iB2 = iB + 32;
            int iC = r2 + off + e32, iC2 = iC + 32;
            int iD = r3 + off + e32, iD2 = iD + 32;
            int sA  = (iA  < r1) ? csr_src[iA]  : -1;
            int sA2 = (iA2 < r1) ? csr_src[iA2] : -1;
            int sB  = (iB  < r2) ? csr_src[iB]  : -1;
            int sB2 = (iB2 < r2) ? csr_src[iB2] : -1;
            int sC  = (iC  < r3) ? csr_src[iC]  : -1;
            int sC2 = (iC2 < r3) ? csr_src[iC2] : -1;
            int sD  = (iD  < r4) ? csr_src[iD]  : -1;
            int sD2 = (iD2 < r4) ? csr_src[iD2] : -1;
            uint4 vA = {0,0,0,0}, vA2 = {0,0,0,0}, vB = {0,0,0,0}, vB2 = {0,0,0,0};
            uint4 vC = {0,0,0,0}, vC2 = {0,0,0,0}, vD = {0,0,0,0}, vD2 = {0,0,0,0};
            if (sA  >= 0) vA  = zr[sA  * 4 + cbase];
            if (sA2 >= 0) vA2 = zr[sA2 * 4 + cbase];
            if (sB  >= 0) vB  = zr[sB  * 4 + cbase];
            if (sB2 >= 0) vB2 = zr[sB2 * 4 + cbase];
            if (sC  >= 0) vC  = zr[sC  * 4 + cbase];
            if (sC2 >= 0) vC2 = zr[sC2 * 4 + cbase];
            if (sD  >= 0) vD  = zr[sD  * 4 + cbase];
            if (sD2 >= 0) vD2 = zr[sD2 * 4 + cbase];
            ACC8(a0, vA, vA2)
            ACC8(a1, vB, vB2)
            ACC8(a2, vC, vC2)
            ACC8(a3, vD, vD2)
        }
#pragma unroll
        for (int m = 2; m <= 32; m <<= 1)
#pragma unroll
            for (int k = 0; k < 8; k++) {
                a0[k] += __shfl_xor(a0[k], m, 64);
                a1[k] += __shfl_xor(a1[k], m, 64);
                a2[k] += __shfl_xor(a2[k], m, 64);
                a3[k] += __shfl_xor(a3[k], m, 64);
            }
        int c = lane & 15, nl = lane >> 4;
        int srcq = (lane >> 3) & 1;
        float v0 = 0, v1 = 0, v2 = 0, v3 = 0;
#pragma unroll
        for (int k = 0; k < 8; k++) {
            float t0 = __shfl(a0[k], srcq, 64);
            float t1 = __shfl(a1[k], srcq, 64);
            float t2 = __shfl(a2[k], srcq, 64);
            float t3 = __shfl(a3[k], srcq, 64);
            bool sel = (lane & 7) == k;
            v0 = sel ? t0 : v0;
            v1 = sel ? t1 : v1;
            v2 = sel ? t2 : v2;
            v3 = sel ? t3 : v3;
        }
        float val = (nl == 0) ? v0 : (nl == 1) ? v1 : (nl == 2) ? v2 : v3;
        int dd = (nl == 0) ? d0 : (nl == 1) ? d1 : (nl == 2) ? d2 : d3;
        int n = nb0 + nl;
        int ch = cz * 16 + c;
        float res = val * (1.0f / fmaxf((float)dd, 1.0f))
                  + b2f(rbuf[(long long)n * 32 + ch]);
        if (isbf)
            ((bf16*)out)[(long long)n * 32 + ch] = __float2bfloat16(res);
        else
            ((float*)out)[(long long)n * 32 + ch] = res;
    }
}

extern "C" void kernel_launch(void* const* d_in, const int* in_sizes, int n_in,
                              void* d_out, int out_size, void* d_ws, size_t ws_size,
                              hipStream_t stream) {
    const void* x = d_in[0];
    const void* ei = d_in[1];  // [2, E]: src = [0,E), dst = [E,2E)
    const void* W1l = d_in[2];
    const void* b1l = d_in[3];
    const void* W1r = d_in[4];
    const void* W2l = d_in[5];
    const void* b2l = d_in[6];
    const void* W2r = d_in[7];

    // workspace layout (~42 MB). aggbuf ALIASES bucket_data (dead after csrB).
    char* ws = (char*)d_ws;
    uint* bucket_data = (uint*)ws;                    // NBKT*BKT_CAP u32 = 16.0 MB
    bf16* aggbuf = (bf16*)ws;                         // N*64 bf16 = 12.8 MB (alias)
    int* csr_src = (int*)(ws + 16015424);             // E i32 = 12.8 MB
    int* row_start = (int*)(ws + 28815424);           // N+1 i32
    int* bucket_cursor = (int*)(ws + 29215488);       // NBKT i32
    int* bucket_base = (int*)(ws + 29217088);         // NBKT i32
    bf16* zbuf = (bf16*)(ws + 29218688);              // N*32 bf16 = 6.4 MB
    bf16* rbuf = (bf16*)(ws + 35618688);              // N*32 bf16 = 6.4 MB
    int* flags = (int*)(ws + 42018688);               // 2 i32

    hipMemsetAsync(bucket_cursor, 0, NBKT * 4, stream);

    detect_kernel<<<1, 64, 0, stream>>>(x, ei, flags);
    scatterA_kernel<<<NBKT, 256, 0, stream>>>(ei, bucket_cursor, bucket_data, flags);
    scanBuckets_kernel<<<1, 512, 0, stream>>>(bucket_cursor, bucket_base);
    csrB_kernel<<<NBKT, 256, 0, stream>>>(bucket_cursor, bucket_base, bucket_data,
                                          csr_src, row_start);
    gather1_kernel<<<4096, 256, 0, stream>>>(x, row_start, csr_src, aggbuf, flags);
    gemm1_kernel<<<1563, 256, 0, stream>>>(x, aggbuf, W1l, b1l, W1r, W2l, b2l,
                                           W2r, zbuf, rbuf, flags);
    node2_kernel<<<4096, 256, 0, stream>>>(row_start, csr_src, zbuf, rbuf, d_out,
                                           flags);
}

// Round 2
// 441.226 us; speedup vs baseline: 1.1027x; 1.1027x over previous
//
#include <hip/hip_runtime.h>
#include <hip/hip_bf16.h>

#define N_NODES 100000
#define N_EDGES 3200000
#define NBKT 391      // ceil(N_NODES/256): bucket = dst>>8
#define BKT_CAP 10240 // avg 8184 edges/bucket, +23 sigma margin

typedef __hip_bfloat16 bf16;
typedef unsigned int uint;
typedef __attribute__((ext_vector_type(8))) short bf16x8;
typedef __attribute__((ext_vector_type(4))) float f32x4;

__device__ __forceinline__ float b2f(bf16 v) { return __bfloat162float(v); }

__device__ __forceinline__ float bits2f(unsigned short w) {
    union { unsigned short u; bf16 b; } c;
    c.u = w;
    return __bfloat162float(c.b);
}
__device__ __forceinline__ unsigned short f2bits(float f) {  // truncate
    return (unsigned short)(__float_as_uint(f) >> 16);
}
__device__ __forceinline__ unsigned short f2bf_bits(float f) {  // RNE
    bf16 b = __float2bfloat16(f);
    unsigned short u;
    __builtin_memcpy(&u, &b, 2);
    return u;
}

// runtime dtype accessors -------------------------------------------------
__device__ __forceinline__ int get_idx(const void* ei, long long pos, int is64) {
    if (is64) return (int)((const long long*)ei)[pos];
    return ((const int*)ei)[pos];
}
__device__ __forceinline__ float get_f(const void* p, long long pos, int isbf) {
    if (isbf) return b2f(((const bf16*)p)[pos]);
    return ((const float*)p)[pos];
}

// ---------------- dtype detection (1 wave) ----------------
__global__ void detect_kernel(const void* __restrict__ x,
                              const void* __restrict__ ei,
                              int* __restrict__ flags) {
    int lane = threadIdx.x;  // 64 threads
    const unsigned short* xw = (const unsigned short*)x;
    float v = bits2f(xw[2 * lane]);
    bool plaus = (v == v) && fabsf(v) > 1e-3f && fabsf(v) < 1e2f;
    unsigned long long m1 = __ballot(plaus);
    const int* iw = (const int*)ei;
    bool z = (iw[2 * lane + 1] == 0);
    unsigned long long m2 = __ballot(z);
    if (lane == 0) {
        flags[0] = (__popcll(m1) >= 32) ? 1 : 0;
        flags[1] = (__popcll(m2) == 64) ? 1 : 0;
    }
}

// ---------------- transpose x -> slice-major xT[4][N][16] (bf16 only) -----
// Each 16-ch slice becomes 3.2 MB CONTIGUOUS (fits a 4 MiB per-XCD L2, and
// cache lines contain only slice data -> no partial-line over-fetch).
__global__ __launch_bounds__(256) void transpose_kernel(
    const void* __restrict__ x, uint4* __restrict__ xt,
    const int* __restrict__ flags) {
    if (!flags[0]) return;  // fp32 path uses original layout
    int i = blockIdx.x * 256 + threadIdx.x;  // N*4 chunks of 32B
    if (i >= N_NODES * 4) return;
    int node = i >> 2, cz = i & 3;
    const uint4* x4 = (const uint4*)x;
    uint4 a = x4[(long long)node * 8 + cz * 2];
    uint4 b = x4[(long long)node * 8 + cz * 2 + 1];
    long long o = (long long)cz * (N_NODES * 2) + (long long)node * 2;
    xt[o] = a;
    xt[o + 1] = b;
}

// ---------------- pass A: bucket edges by dst>>8 ----------------
__global__ __launch_bounds__(256) void scatterA_kernel(
    const void* __restrict__ ei, int* __restrict__ bucket_cursor,
    uint* __restrict__ bucket_data, const int* __restrict__ flags) {
    __shared__ int lhist[NBKT];
    __shared__ int lbase[NBKT];
    int is64 = flags[1];
    int t = threadIdx.x;
    int chunk0 = blockIdx.x * 8192;
    int dreg[32];

    for (int i = t; i < NBKT; i += 256) lhist[i] = 0;
    __syncthreads();
#pragma unroll
    for (int j = 0; j < 32; j++) {
        int e = chunk0 + j * 256 + t;
        int d = -1;
        if (e < N_EDGES) {
            d = get_idx(ei, (long long)N_EDGES + e, is64);
            atomicAdd(&lhist[d >> 8], 1);
        }
        dreg[j] = d;
    }
    __syncthreads();
    for (int i = t; i < NBKT; i += 256) {
        int c = lhist[i];
        lbase[i] = c ? atomicAdd(&bucket_cursor[i], c) : 0;
        lhist[i] = 0;  // reuse as local cursor
    }
    __syncthreads();
#pragma unroll
    for (int j = 0; j < 32; j++) {
        int e = chunk0 + j * 256 + t;
        int d = dreg[j];
        if (d >= 0) {
            int s = get_idx(ei, e, is64);
            int b = d >> 8;
            int o = lbase[b] + atomicAdd(&lhist[b], 1);
            if (o < BKT_CAP)
                bucket_data[(long long)b * BKT_CAP + o] = ((uint)(d & 255) << 17) | (uint)s;
        }
    }
}

// ---------------- scan bucket counts -> bucket base ----------------
__global__ void scanBuckets_kernel(const int* __restrict__ cnt,
                                   int* __restrict__ base) {
    __shared__ int buf[512];
    int t = threadIdx.x;  // 512 threads
    int v = (t < NBKT) ? cnt[t] : 0;
    buf[t] = v;
    __syncthreads();
    for (int off = 1; off < 512; off <<= 1) {
        int add = (t >= off) ? buf[t - off] : 0;
        __syncthreads();
        buf[t] += add;
        __syncthreads();
    }
    if (t < NBKT) base[t] = buf[t] - v;  // exclusive
}

// ---------------- pass B: per-bucket CSR build ----------------
__global__ __launch_bounds__(256) void csrB_kernel(
    const int* __restrict__ bucket_cnt, const int* __restrict__ bucket_base,
    const uint* __restrict__ bucket_data, int* __restrict__ csr_src,
    int* __restrict__ row_start) {
    __shared__ int lh[256];
    __shared__ int buf[256];
    int b = blockIdx.x;
    int t = threadIdx.x;
    int cnt = bucket_cnt[b];
    if (cnt > BKT_CAP) cnt = BKT_CAP;
    int base = bucket_base[b];
    const uint* bd = bucket_data + (long long)b * BKT_CAP;

    lh[t] = 0;
    __syncthreads();
    for (int i = t; i < cnt; i += 256) atomicAdd(&lh[bd[i] >> 17], 1);
    __syncthreads();
    int v = lh[t];
    buf[t] = v;
    __syncthreads();
    for (int off = 1; off < 256; off <<= 1) {
        int add = (t >= off) ? buf[t - off] : 0;
        __syncthreads();
        buf[t] += add;
        __syncthreads();
    }
    int excl = buf[t] - v;
    int g = (b << 8) + t;
    if (g < N_NODES) row_start[g] = base + excl;
    lh[t] = excl;  // reuse as local cursor
    __syncthreads();
    for (int i = t; i < cnt; i += 256) {
        uint e = bd[i];
        int o = atomicAdd(&lh[e >> 17], 1);
        csr_src[base + o] = (int)(e & 0x1FFFFu);
    }
    if (b == 0 && t == 0) row_start[N_NODES] = N_EDGES;
}

// unpack-accumulate helpers ----------------------------------------------
#define ACC8(acc, v, v2)                                                         \
    acc[0] += __uint_as_float((v).x << 16) + __uint_as_float((v2).x << 16);       \
    acc[1] += __uint_as_float((v).x & 0xffff0000u) + __uint_as_float((v2).x & 0xffff0000u); \
    acc[2] += __uint_as_float((v).y << 16) + __uint_as_float((v2).y << 16);       \
    acc[3] += __uint_as_float((v).y & 0xffff0000u) + __uint_as_float((v2).y & 0xffff0000u); \
    acc[4] += __uint_as_float((v).z << 16) + __uint_as_float((v2).z << 16);       \
    acc[5] += __uint_as_float((v).z & 0xffff0000u) + __uint_as_float((v2).z & 0xffff0000u); \
    acc[6] += __uint_as_float((v).w << 16) + __uint_as_float((v2).w << 16);       \
    acc[7] += __uint_as_float((v).w & 0xffff0000u) + __uint_as_float((v2).w & 0xffff0000u);

#define ACCF4(acc, v, v2)                                                        \
    acc[0] += __uint_as_float((v).x) + __uint_as_float((v2).x);                   \
    acc[1] += __uint_as_float((v).y) + __uint_as_float((v2).y);                   \
    acc[2] += __uint_as_float((v).z) + __uint_as_float((v2).z);                   \
    acc[3] += __uint_as_float((v).w) + __uint_as_float((v2).w);

// ---------------- layer-1 gather (bf16: channel-sliced over xT) ----------
// 4 slices x 16ch; slice cz pinned to XCD pair via bid%8 round-robin.
// xT slice = 3.2 MB contiguous -> per-XCD-L2 resident. fp32 path: round-0
// full-row gather against original x (no slicing).
__global__ __launch_bounds__(256) void gather1_kernel(
    const void* __restrict__ x, const uint4* __restrict__ xt,
    const int* __restrict__ row_start, const int* __restrict__ csr_src,
    bf16* __restrict__ aggbuf, const int* __restrict__ flags) {
    int isbf = flags[0];
    int t = threadIdx.x;
    int lane = t & 63;
    int w = t >> 6;
    int bid = blockIdx.x;

    if (isbf) {
        int cz = (bid & 7) >> 1;                               // slice 0..3
        int wid = ((((bid >> 3) << 1) | (bid & 1)) << 2) + w;  // wave id in slice
        int nw = gridDim.x;                                    // waves per slice
        int e32 = lane >> 1, q2 = lane & 1;
        const uint4* xs = xt + (long long)cz * (N_NODES * 2);  // slice base
        for (int quad = wid; quad < N_NODES / 4; quad += nw) {
            int nb0 = quad * 4;
            int r0 = row_start[nb0], r1 = row_start[nb0 + 1],
                r2 = row_start[nb0 + 2], r3 = row_start[nb0 + 3],
                r4 = row_start[nb0 + 4];
            int d0 = r1 - r0, d1 = r2 - r1, d2 = r3 - r2, d3 = r4 - r3;
            int maxd = max(max(d0, d1), max(d2, d3));
            float a0[8] = {0,0,0,0,0,0,0,0}, a1[8] = {0,0,0,0,0,0,0,0};
            float a2[8] = {0,0,0,0,0,0,0,0}, a3[8] = {0,0,0,0,0,0,0,0};
            for (int off = 0; off < maxd; off += 64) {
                int iA = r0 + off + e32, iA2 = iA + 32;
                int iB = r1 + off + e32, iB2 = iB + 32;
                int iC = r2 + off + e32, iC2 = iC + 32;
                int iD = r3 + off + e32, iD2 = iD + 32;
                int sA  = (iA  < r1) ? csr_src[iA]  : -1;
                int sA2 = (iA2 < r1) ? csr_src[iA2] : -1;
                int sB  = (iB  < r2) ? csr_src[iB]  : -1;
                int sB2 = (iB2 < r2) ? csr_src[iB2] : -1;
                int sC  = (iC  < r3) ? csr_src[iC]  : -1;
                int sC2 = (iC2 < r3) ? csr_src[iC2] : -1;
                int sD  = (iD  < r4) ? csr_src[iD]  : -1;
                int sD2 = (iD2 < r4) ? csr_src[iD2] : -1;
                uint4 vA = {0,0,0,0}, vA2 = {0,0,0,0}, vB = {0,0,0,0}, vB2 = {0,0,0,0};
                uint4 vC = {0,0,0,0}, vC2 = {0,0,0,0}, vD = {0,0,0,0}, vD2 = {0,0,0,0};
                if (sA  >= 0) vA  = xs[(sA  << 1) + q2];
                if (sA2 >= 0) vA2 = xs[(sA2 << 1) + q2];
                if (sB  >= 0) vB  = xs[(sB  << 1) + q2];
                if (sB2 >= 0) vB2 = xs[(sB2 << 1) + q2];
                if (sC  >= 0) vC  = xs[(sC  << 1) + q2];
                if (sC2 >= 0) vC2 = xs[(sC2 << 1) + q2];
                if (sD  >= 0) vD  = xs[(sD  << 1) + q2];
                if (sD2 >= 0) vD2 = xs[(sD2 << 1) + q2];
                ACC8(a0, vA, vA2)
                ACC8(a1, vB, vB2)
                ACC8(a2, vC, vC2)
                ACC8(a3, vD, vD2)
            }
#pragma unroll
            for (int m = 2; m <= 32; m <<= 1)
#pragma unroll
                for (int k = 0; k < 8; k++) {
                    a0[k] += __shfl_xor(a0[k], m, 64);
                    a1[k] += __shfl_xor(a1[k], m, 64);
                    a2[k] += __shfl_xor(a2[k], m, 64);
                    a3[k] += __shfl_xor(a3[k], m, 64);
                }
            int c = lane & 15, nl = lane >> 4;
            int srcq = (lane >> 3) & 1;
            float v0 = 0, v1 = 0, v2 = 0, v3 = 0;
#pragma unroll
            for (int k = 0; k < 8; k++) {
                float t0 = __shfl(a0[k], srcq, 64);
                float t1 = __shfl(a1[k], srcq, 64);
                float t2 = __shfl(a2[k], srcq, 64);
                float t3 = __shfl(a3[k], srcq, 64);
                bool sel = (lane & 7) == k;
                v0 = sel ? t0 : v0;
                v1 = sel ? t1 : v1;
                v2 = sel ? t2 : v2;
                v3 = sel ? t3 : v3;
            }
            float val = (nl == 0) ? v0 : (nl == 1) ? v1 : (nl == 2) ? v2 : v3;
            int dd = (nl == 0) ? d0 : (nl == 1) ? d1 : (nl == 2) ? d2 : d3;
            val *= 1.0f / fmaxf((float)dd, 1.0f);
            aggbuf[(long long)(nb0 + nl) * 64 + cz * 16 + c] = __float2bfloat16(val);
        }
    } else {
        // fp32 fallback: full-row gather over original x (round-0 code)
        int gw = (bid * 256 + t) >> 6;
        int nwv = (gridDim.x * 256) >> 6;
        int e4 = lane >> 4, q16 = lane & 15;
        const uint4* xf = (const uint4*)x;  // fp32 row = 16 uint4
        for (int p = gw; p * 2 < N_NODES; p += nwv) {
            int na = p * 2, nb = p * 2 + 1;
            int sa = row_start[na], ea = row_start[na + 1];
            int sb = row_start[nb], eb = row_start[nb + 1];
            int da = ea - sa, db = eb - sb;
            int maxd = max(da, db);
            float accA[4] = {0, 0, 0, 0};
            float accB[4] = {0, 0, 0, 0};
            for (int off = 0; off < maxd; off += 16) {
                int iA0 = sa + off + e4, iA1 = iA0 + 4, iA2 = iA0 + 8, iA3 = iA0 + 12;
                int iB0 = sb + off + e4, iB1 = iB0 + 4, iB2 = iB0 + 8, iB3 = iB0 + 12;
                int sA0 = (iA0 < ea) ? csr_src[iA0] : -1;
                int sA1 = (iA1 < ea) ? csr_src[iA1] : -1;
                int sA2 = (iA2 < ea) ? csr_src[iA2] : -1;
                int sA3 = (iA3 < ea) ? csr_src[iA3] : -1;
                int sB0 = (iB0 < eb) ? csr_src[iB0] : -1;
                int sB1 = (iB1 < eb) ? csr_src[iB1] : -1;
                int sB2 = (iB2 < eb) ? csr_src[iB2] : -1;
                int sB3 = (iB3 < eb) ? csr_src[iB3] : -1;
                uint4 vA0 = {0,0,0,0}, vA1 = {0,0,0,0}, vA2 = {0,0,0,0}, vA3 = {0,0,0,0};
                uint4 vB0 = {0,0,0,0}, vB1 = {0,0,0,0}, vB2 = {0,0,0,0}, vB3 = {0,0,0,0};
                if (sA0 >= 0) vA0 = xf[sA0 * 16 + q16];
                if (sA1 >= 0) vA1 = xf[sA1 * 16 + q16];
                if (sA2 >= 0) vA2 = xf[sA2 * 16 + q16];
                if (sA3 >= 0) vA3 = xf[sA3 * 16 + q16];
                if (sB0 >= 0) vB0 = xf[sB0 * 16 + q16];
                if (sB1 >= 0) vB1 = xf[sB1 * 16 + q16];
                if (sB2 >= 0) vB2 = xf[sB2 * 16 + q16];
                if (sB3 >= 0) vB3 = xf[sB3 * 16 + q16];
                ACCF4(accA, vA0, vA1)
                ACCF4(accA, vA2, vA3)
                ACCF4(accB, vB0, vB1)
                ACCF4(accB, vB2, vB3)
            }
#pragma unroll
            for (int m = 16; m <= 32; m <<= 1)
#pragma unroll
                for (int k = 0; k < 4; k++) {
                    accA[k] += __shfl_xor(accA[k], m, 64);
                    accB[k] += __shfl_xor(accB[k], m, 64);
                }
            float avA = 0.0f, avB = 0.0f;
#pragma unroll
            for (int k = 0; k < 4; k++) {
                float vA = __shfl(accA[k], lane >> 2, 64);
                float vB = __shfl(accB[k], lane >> 2, 64);
                avA = ((lane & 3) == k) ? vA : avA;
                avB = ((lane & 3) == k) ? vB : avB;
            }
            avA *= 1.0f / fmaxf((float)da, 1.0f);
            avB *= 1.0f / fmaxf((float)db, 1.0f);
            aggbuf[(long long)na * 64 + lane] = __float2bfloat16(avA);
            aggbuf[(long long)nb * 64 + lane] = __float2bfloat16(avB);
        }
    }
}

// ---------------- layer-1+2 GEMMs (MFMA, dense coalesced staging) ----------------
// Writes z/r slice-major: zbufT[2][N][16], rbufT[2][N][16] (for node2's L2 slicing).
__global__ __launch_bounds__(256) void gemm1_kernel(
    const void* __restrict__ x, const bf16* __restrict__ aggbuf,
    const void* __restrict__ W1l, const void* __restrict__ b1l,
    const void* __restrict__ W1r, const void* __restrict__ W2l,
    const void* __restrict__ b2l, const void* __restrict__ W2r,
    bf16* __restrict__ zbufT, bf16* __restrict__ rbufT,
    const int* __restrict__ flags) {
    __shared__ __align__(16) unsigned short sW1t[64][136];
    __shared__ __align__(16) unsigned short sA[64][136];
    __shared__ __align__(16) unsigned short sW2t[64][72];
    __shared__ __align__(16) unsigned short sH[64][72];
    __shared__ float sB1[64];
    __shared__ float sB2[32];

    int isbf = flags[0];
    int t = threadIdx.x;
    int n0 = blockIdx.x * 64;

    for (int i = t; i < 64 * 128; i += 256) {
        int n = i & 63, k = i >> 6;
        unsigned short v;
        if (isbf)
            v = (k < 64) ? ((const unsigned short*)W1l)[k * 64 + n]
                         : ((const unsigned short*)W1r)[(k - 64) * 64 + n];
        else
            v = f2bits((k < 64) ? ((const float*)W1l)[k * 64 + n]
                                : ((const float*)W1r)[(k - 64) * 64 + n]);
        sW1t[n][k] = v;
    }
    for (int i = t; i < 64 * 64; i += 256) {
        int n = i & 63, k = i >> 6;
        unsigned short v;
        if (isbf)
            v = (n < 32) ? ((const unsigned short*)W2l)[k * 32 + n]
                         : ((const unsigned short*)W2r)[k * 32 + (n - 32)];
        else
            v = f2bits((n < 32) ? ((const float*)W2l)[k * 32 + n]
                                : ((const float*)W2r)[k * 32 + (n - 32)]);
        sW2t[n][k] = v;
    }
    if (t < 64) sB1[t] = get_f(b1l, t, isbf);
    if (t < 32) sB2[t] = get_f(b2l, t, isbf);

    const uint4* ag4 = (const uint4*)aggbuf;
    if (isbf) {
        const uint4* x4 = (const uint4*)x;
        for (int i = t; i < 64 * 16; i += 256) {
            int m = i >> 4, c = i & 15;
            int nn = min(n0 + m, N_NODES - 1);
            uint4 v = (c < 8) ? ag4[(long long)nn * 8 + c]
                              : x4[(long long)nn * 8 + (c - 8)];
            *(uint4*)&sA[m][c * 8] = v;
        }
    } else {
        for (int i = t; i < 64 * 8; i += 256) {
            int m = i >> 3, c = i & 7;
            int nn = min(n0 + m, N_NODES - 1);
            *(uint4*)&sA[m][c * 8] = ag4[(long long)nn * 8 + c];
        }
        const float* xf = (const float*)x;
        for (int i = t; i < 64 * 64; i += 256) {
            int m = i >> 6, c = i & 63;
            int nn = min(n0 + m, N_NODES - 1);
            sA[m][64 + c] = f2bf_bits(xf[(long long)nn * 64 + c]);
        }
    }
    __syncthreads();

    int w = t >> 6, lane = t & 63;
    int mbase = w * 16;
    int q = lane >> 4, r15 = lane & 15;
    f32x4 acc1[4] = {{0,0,0,0},{0,0,0,0},{0,0,0,0},{0,0,0,0}};
#pragma unroll
    for (int ks = 0; ks < 4; ks++) {
        bf16x8 afrag = *(const bf16x8*)&sA[mbase + r15][ks * 32 + q * 8];
#pragma unroll
        for (int nt = 0; nt < 4; nt++) {
            bf16x8 bfrag = *(const bf16x8*)&sW1t[nt * 16 + r15][ks * 32 + q * 8];
            acc1[nt] = __builtin_amdgcn_mfma_f32_16x16x32_bf16(afrag, bfrag, acc1[nt], 0, 0, 0);
        }
    }
#pragma unroll
    for (int nt = 0; nt < 4; nt++) {
        int col = nt * 16 + r15;
        float bias = sB1[col];
#pragma unroll
        for (int rr = 0; rr < 4; rr++) {
            int m = mbase + q * 4 + rr;
            sH[m][col] = f2bf_bits(fmaxf(acc1[nt][rr] + bias, 0.0f));
        }
    }
    __syncthreads();

    f32x4 acc2[4] = {{0,0,0,0},{0,0,0,0},{0,0,0,0},{0,0,0,0}};
#pragma unroll
    for (int ks = 0; ks < 2; ks++) {
        bf16x8 afrag = *(const bf16x8*)&sH[mbase + r15][ks * 32 + q * 8];
#pragma unroll
        for (int nt = 0; nt < 4; nt++) {
            bf16x8 bfrag = *(const bf16x8*)&sW2t[nt * 16 + r15][ks * 32 + q * 8];
            acc2[nt] = __builtin_amdgcn_mfma_f32_16x16x32_bf16(afrag, bfrag, acc2[nt], 0, 0, 0);
        }
    }
#pragma unroll
    for (int nt = 0; nt < 4; nt++) {
        int col = nt * 16 + r15;
#pragma unroll
        for (int rr = 0; rr < 4; rr++) {
            int m = mbase + q * 4 + rr;
            int n = n0 + m;
            if (n < N_NODES) {
                float v = acc2[nt][rr];
                if (col < 32) {
                    zbufT[(long long)(col >> 4) * (N_NODES * 16) +
                          (long long)n * 16 + (col & 15)] = __float2bfloat16(v);
                } else {
                    int c2 = col - 32;
                    rbufT[(long long)(c2 >> 4) * (N_NODES * 16) +
                          (long long)n * 16 + (c2 & 15)] =
                        __float2bfloat16(v + sB2[c2]);
                }
            }
        }
    }
}

// ---------------- layer-2: gather z (slice-major), 2 slices x 16ch ----------------
// zT slice = 3.2 MB contiguous; cz = (bid%8)>>2 pins slice to 4 XCDs.
__global__ __launch_bounds__(256) void node2_kernel(
    const int* __restrict__ row_start, const int* __restrict__ csr_src,
    const bf16* __restrict__ zT, const bf16* __restrict__ rbufT,
    void* __restrict__ out, const int* __restrict__ flags) {
    int isbf = flags[0];
    int t = threadIdx.x;
    int lane = t & 63;
    int w = t >> 6;
    int bid = blockIdx.x;
    int cz = (bid & 7) >> 2;                                   // slice 0..1
    int wid = ((((bid >> 3) << 2) | (bid & 3)) << 2) + w;      // wave id within cz
    int nw = gridDim.x * 2;                                    // waves per cz
    const uint4* zs = (const uint4*)zT + (long long)cz * (N_NODES * 2);
    const bf16* rs = rbufT + (long long)cz * (N_NODES * 16);

    int e32 = lane >> 1, q2 = lane & 1;
    for (int quad = wid; quad < N_NODES / 4; quad += nw) {
        int nb0 = quad * 4;
        int r0 = row_start[nb0], r1 = row_start[nb0 + 1],
            r2 = row_start[nb0 + 2], r3 = row_start[nb0 + 3],
            r4 = row_start[nb0 + 4];
        int d0 = r1 - r0, d1 = r2 - r1, d2 = r3 - r2, d3 = r4 - r3;
        int maxd = max(max(d0, d1), max(d2, d3));
        float a0[8] = {0,0,0,0,0,0,0,0}, a1[8] = {0,0,0,0,0,0,0,0};
        float a2[8] = {0,0,0,0,0,0,0,0}, a3[8] = {0,0,0,0,0,0,0,0};
        for (int off = 0; off < maxd; off += 64) {
            int iA = r0 + off + e32, iA2 = iA + 32;
            int iB = r1 + off + e32, iB2 = iB + 32;
            int iC = r2 + off + e32, iC2 = iC + 32;
            int iD = r3 + off + e32, iD2 = iD + 32;
            int sA  = (iA  < r1) ? csr_src[iA]  : -1;
            int sA2 = (iA2 < r1) ? csr_src[iA2] : -1;
            int sB  = (iB  < r2) ? csr_src[iB]  : -1;
            int sB2 = (iB2 < r2) ? csr_src[iB2] : -1;
            int sC  = (iC  < r3) ? csr_src[iC]  : -1;
            int sC2 = (iC2 < r3) ? csr_src[iC2] : -1;
            int sD  = (iD  < r4) ? csr_src[iD]  : -1;
            int sD2 = (iD2 < r4) ? csr_src[iD2] : -1;
            uint4 vA = {0,0,0,0}, vA2 = {0,0,0,0}, vB = {0,0,0,0}, vB2 = {0,0,0,0};
            uint4 vC = {0,0,0,0}, vC2 = {0,0,0,0}, vD = {0,0,0,0}, vD2 = {0,0,0,0};
            if (sA  >= 0) vA  = zs[(sA  << 1) + q2];
            if (sA2 >= 0) vA2 = zs[(sA2 << 1) + q2];
            if (sB  >= 0) vB  = zs[(sB  << 1) + q2];
            if (sB2 >= 0) vB2 = zs[(sB2 << 1) + q2];
            if (sC  >= 0) vC  = zs[(sC  << 1) + q2];
            if (sC2 >= 0) vC2 = zs[(sC2 << 1) + q2];
            if (sD  >= 0) vD  = zs[(sD  << 1) + q2];
            if (sD2 >= 0) vD2 = zs[(sD2 << 1) + q2];
            ACC8(a0, vA, vA2)
            ACC8(a1, vB, vB2)
            ACC8(a2, vC, vC2)
            ACC8(a3, vD, vD2)
        }
#pragma unroll
        for (int m = 2; m <= 32; m <<= 1)
#pragma unroll
            for (int k = 0; k < 8; k++) {
                a0[k] += __shfl_xor(a0[k], m, 64);
                a1[k] += __shfl_xor(a1[k], m, 64);
                a2[k] += __shfl_xor(a2[k], m, 64);
                a3[k] += __shfl_xor(a3[k], m, 64);
            }
        int c = lane & 15, nl = lane >> 4;
        int srcq = (lane >> 3) & 1;
        float v0 = 0, v1 = 0, v2 = 0, v3 = 0;
#pragma unroll
        for (int k = 0; k < 8; k++) {
            float t0 = __shfl(a0[k], srcq, 64);
            float t1 = __shfl(a1[k], srcq, 64);
            float t2 = __shfl(a2[k], srcq, 64);
            float t3 = __shfl(a3[k], srcq, 64);
            bool sel = (lane & 7) == k;
            v0 = sel ? t0 : v0;
            v1 = sel ? t1 : v1;
            v2 = sel ? t2 : v2;
            v3 = sel ? t3 : v3;
        }
        float val = (nl == 0) ? v0 : (nl == 1) ? v1 : (nl == 2) ? v2 : v3;
        int dd = (nl == 0) ? d0 : (nl == 1) ? d1 : (nl == 2) ? d2 : d3;
        int n = nb0 + nl;
        int ch = cz * 16 + c;
        float res = val * (1.0f / fmaxf((float)dd, 1.0f))
                  + b2f(rs[(long long)n * 16 + c]);
        if (isbf)
            ((bf16*)out)[(long long)n * 32 + ch] = __float2bfloat16(res);
        else
            ((float*)out)[(long long)n * 32 + ch] = res;
    }
}

extern "C" void kernel_launch(void* const* d_in, const int* in_sizes, int n_in,
                              void* d_out, int out_size, void* d_ws, size_t ws_size,
                              hipStream_t stream) {
    const void* x = d_in[0];
    const void* ei = d_in[1];  // [2, E]: src = [0,E), dst = [E,2E)
    const void* W1l = d_in[2];
    const void* b1l = d_in[3];
    const void* W1r = d_in[4];
    const void* W2l = d_in[5];
    const void* b2l = d_in[6];
    const void* W2r = d_in[7];

    // workspace layout (~42 MB), triple-aliased across pipeline phases:
    //   [0, 16.0MB)      bucket_data (dead after csrB)  / aggbuf (gather1->gemm1)
    //   [29.2, 42.0MB)   xT (transpose->gather1, bf16)  / zbufT+rbufT (gemm1->node2)
    char* ws = (char*)d_ws;
    uint* bucket_data = (uint*)ws;                    // NBKT*BKT_CAP u32 = 16.0 MB
    bf16* aggbuf = (bf16*)ws;                         // N*64 bf16 = 12.8 MB (alias)
    int* csr_src = (int*)(ws + 16015424);             // E i32 = 12.8 MB
    int* row_start = (int*)(ws + 28815424);           // N+1 i32
    int* bucket_cursor = (int*)(ws + 29215488);       // NBKT i32
    int* bucket_base = (int*)(ws + 29217088);         // NBKT i32
    uint4* xt = (uint4*)(ws + 29218688);              // 4*N*16 bf16 = 12.8 MB (alias)
    bf16* zbufT = (bf16*)(ws + 29218688);             // 2*N*16 bf16 = 6.4 MB
    bf16* rbufT = (bf16*)(ws + 35618688);             // 2*N*16 bf16 = 6.4 MB
    int* flags = (int*)(ws + 42018688);               // 2 i32

    hipMemsetAsync(bucket_cursor, 0, NBKT * 4, stream);

    detect_kernel<<<1, 64, 0, stream>>>(x, ei, flags);
    transpose_kernel<<<1563, 256, 0, stream>>>(x, xt, flags);
    scatterA_kernel<<<NBKT, 256, 0, stream>>>(ei, bucket_cursor, bucket_data, flags);
    scanBuckets_kernel<<<1, 512, 0, stream>>>(bucket_cursor, bucket_base);
    csrB_kernel<<<NBKT, 256, 0, stream>>>(bucket_cursor, bucket_base, bucket_data,
                                          csr_src, row_start);
    gather1_kernel<<<4096, 256, 0, stream>>>(x, xt, row_start, csr_src, aggbuf,
                                             flags);
    gemm1_kernel<<<1563, 256, 0, stream>>>(x, aggbuf, W1l, b1l, W1r, W2l, b2l,
                                           W2r, zbufT, rbufT, flags);
    node2_kernel<<<4096, 256, 0, stream>>>(row_start, csr_src, zbufT, rbufT,
                                           d_out, flags);
}

// Round 3
// 374.391 us; speedup vs baseline: 1.2996x; 1.1785x over previous
//
#include <hip/hip_runtime.h>
#include <hip/hip_bf16.h>

#define N_NODES 100000
#define N_EDGES 3200000
#define NBKT 391      // ceil(N_NODES/256): bucket = dst>>8
#define BKT_CAP 10240 // avg 8184 edges/bucket, +23 sigma margin

typedef __hip_bfloat16 bf16;
typedef unsigned int uint;
typedef __attribute__((ext_vector_type(8))) short bf16x8;
typedef __attribute__((ext_vector_type(4))) float f32x4;

__device__ __forceinline__ float b2f(bf16 v) { return __bfloat162float(v); }

__device__ __forceinline__ float bits2f(unsigned short w) {
    union { unsigned short u; bf16 b; } c;
    c.u = w;
    return __bfloat162float(c.b);
}
__device__ __forceinline__ unsigned short f2bits(float f) {  // truncate
    return (unsigned short)(__float_as_uint(f) >> 16);
}
__device__ __forceinline__ unsigned short f2bf_bits(float f) {  // RNE
    bf16 b = __float2bfloat16(f);
    unsigned short u;
    __builtin_memcpy(&u, &b, 2);
    return u;
}
__device__ __forceinline__ float lo16f(uint w) { return __uint_as_float(w << 16); }
__device__ __forceinline__ float hi16f(uint w) { return __uint_as_float(w & 0xffff0000u); }

// runtime dtype accessors -------------------------------------------------
__device__ __forceinline__ int get_idx(const void* ei, long long pos, int is64) {
    if (is64) return (int)((const long long*)ei)[pos];
    return ((const int*)ei)[pos];
}
__device__ __forceinline__ float get_f(const void* p, long long pos, int isbf) {
    if (isbf) return b2f(((const bf16*)p)[pos]);
    return ((const float*)p)[pos];
}

// ---------------- dtype detection (1 wave) ----------------
__global__ void detect_kernel(const void* __restrict__ x,
                              const void* __restrict__ ei,
                              int* __restrict__ flags) {
    int lane = threadIdx.x;  // 64 threads
    const unsigned short* xw = (const unsigned short*)x;
    float v = bits2f(xw[2 * lane]);
    bool plaus = (v == v) && fabsf(v) > 1e-3f && fabsf(v) < 1e2f;
    unsigned long long m1 = __ballot(plaus);
    const int* iw = (const int*)ei;
    bool z = (iw[2 * lane + 1] == 0);
    unsigned long long m2 = __ballot(z);
    if (lane == 0) {
        flags[0] = (__popcll(m1) >= 32) ? 1 : 0;
        flags[1] = (__popcll(m2) == 64) ? 1 : 0;
    }
}

// ---------------- transpose x -> slice-major xT[4][N][16] (bf16 only) -----
// Each 16-ch slice = 3.2 MB CONTIGUOUS (per-XCD-L2-resident; full-line use).
__global__ __launch_bounds__(256) void transpose_kernel(
    const void* __restrict__ x, uint4* __restrict__ xt,
    const int* __restrict__ flags) {
    if (!flags[0]) return;  // fp32 path uses original layout
    int i = blockIdx.x * 256 + threadIdx.x;  // N*4 chunks of 32B
    if (i >= N_NODES * 4) return;
    int node = i >> 2, cz = i & 3;
    const uint4* x4 = (const uint4*)x;
    uint4 a = x4[(long long)node * 8 + cz * 2];
    uint4 b = x4[(long long)node * 8 + cz * 2 + 1];
    long long o = (long long)cz * (N_NODES * 2) + (long long)node * 2;
    xt[o] = a;
    xt[o + 1] = b;
}

// ---------------- pass A: bucket edges by dst>>8 ----------------
__global__ __launch_bounds__(256) void scatterA_kernel(
    const void* __restrict__ ei, int* __restrict__ bucket_cursor,
    uint* __restrict__ bucket_data, const int* __restrict__ flags) {
    __shared__ int lhist[NBKT];
    __shared__ int lbase[NBKT];
    int is64 = flags[1];
    int t = threadIdx.x;
    int chunk0 = blockIdx.x * 8192;
    int dreg[32];

    for (int i = t; i < NBKT; i += 256) lhist[i] = 0;
    __syncthreads();
#pragma unroll
    for (int j = 0; j < 32; j++) {
        int e = chunk0 + j * 256 + t;
        int d = -1;
        if (e < N_EDGES) {
            d = get_idx(ei, (long long)N_EDGES + e, is64);
            atomicAdd(&lhist[d >> 8], 1);
        }
        dreg[j] = d;
    }
    __syncthreads();
    for (int i = t; i < NBKT; i += 256) {
        int c = lhist[i];
        lbase[i] = c ? atomicAdd(&bucket_cursor[i], c) : 0;
        lhist[i] = 0;  // reuse as local cursor
    }
    __syncthreads();
#pragma unroll
    for (int j = 0; j < 32; j++) {
        int e = chunk0 + j * 256 + t;
        int d = dreg[j];
        if (d >= 0) {
            int s = get_idx(ei, e, is64);
            int b = d >> 8;
            int o = lbase[b] + atomicAdd(&lhist[b], 1);
            if (o < BKT_CAP)
                bucket_data[(long long)b * BKT_CAP + o] = ((uint)(d & 255) << 17) | (uint)s;
        }
    }
}

// ---------------- scan bucket counts -> bucket base ----------------
__global__ void scanBuckets_kernel(const int* __restrict__ cnt,
                                   int* __restrict__ base) {
    __shared__ int buf[512];
    int t = threadIdx.x;  // 512 threads
    int v = (t < NBKT) ? cnt[t] : 0;
    buf[t] = v;
    __syncthreads();
    for (int off = 1; off < 512; off <<= 1) {
        int add = (t >= off) ? buf[t - off] : 0;
        __syncthreads();
        buf[t] += add;
        __syncthreads();
    }
    if (t < NBKT) base[t] = buf[t] - v;  // exclusive
}

// ---------------- pass B: per-bucket CSR build ----------------
__global__ __launch_bounds__(256) void csrB_kernel(
    const int* __restrict__ bucket_cnt, const int* __restrict__ bucket_base,
    const uint* __restrict__ bucket_data, int* __restrict__ csr_src,
    int* __restrict__ row_start) {
    __shared__ int lh[256];
    __shared__ int buf[256];
    int b = blockIdx.x;
    int t = threadIdx.x;
    int cnt = bucket_cnt[b];
    if (cnt > BKT_CAP) cnt = BKT_CAP;
    int base = bucket_base[b];
    const uint* bd = bucket_data + (long long)b * BKT_CAP;

    lh[t] = 0;
    __syncthreads();
    for (int i = t; i < cnt; i += 256) atomicAdd(&lh[bd[i] >> 17], 1);
    __syncthreads();
    int v = lh[t];
    buf[t] = v;
    __syncthreads();
    for (int off = 1; off < 256; off <<= 1) {
        int add = (t >= off) ? buf[t - off] : 0;
        __syncthreads();
        buf[t] += add;
        __syncthreads();
    }
    int excl = buf[t] - v;
    int g = (b << 8) + t;
    if (g < N_NODES) row_start[g] = base + excl;
    lh[t] = excl;  // reuse as local cursor
    __syncthreads();
    for (int i = t; i < cnt; i += 256) {
        uint e = bd[i];
        int o = atomicAdd(&lh[e >> 17], 1);
        csr_src[base + o] = (int)(e & 0x1FFFFu);
    }
    if (b == 0 && t == 0) row_start[N_NODES] = N_EDGES;
}

#define ACCF4(acc, v, v2)                                                        \
    acc[0] += __uint_as_float((v).x) + __uint_as_float((v2).x);                   \
    acc[1] += __uint_as_float((v).y) + __uint_as_float((v2).y);                   \
    acc[2] += __uint_as_float((v).z) + __uint_as_float((v2).z);                   \
    acc[3] += __uint_as_float((v).w) + __uint_as_float((v2).w);

// ---- shared slice-gather core: 8 nodes/wave, 8 lanes/node, 2ch/lane ------
// slice = [N][16] bf16 viewed as uint[N*8]. In-lane accumulation: NO
// reduction shuffles; one src-broadcast shuffle per edge. Returns a0/a1
// (lo/hi channel) and dg for this lane's node.
__device__ __forceinline__ void slice_gather8(
    const uint* __restrict__ su, const int* __restrict__ row_start,
    const int* __restrict__ csr_src, int nb0, int g8, int c8, int lane,
    float& a0, float& a1, int& dg_out) {
    // lanes 0..8 load row_start[nb0+l]; groups read their own bounds
    int rl = (lane <= 8) ? row_start[nb0 + lane] : 0;
    int sg = __shfl(rl, g8 >> 3, 64);
    int eg = __shfl(rl, (g8 >> 3) + 1, 64);
    int dg = eg - sg;
    // wave-uniform maxd: groups g^1,g^2,g^4 live at lane^8,^16,^32
    int maxd = dg;
    maxd = max(maxd, __shfl_xor(maxd, 8, 64));
    maxd = max(maxd, __shfl_xor(maxd, 16, 64));
    maxd = max(maxd, __shfl_xor(maxd, 32, 64));

    float s0f = 0.0f, s1f = 0.0f;
    for (int base = 0; base < maxd; base += 8) {
        int pf = sg + base + c8;
        int sreg = (pf < eg) ? csr_src[pf] : 0;
#pragma unroll
        for (int u = 0; u < 8; u += 4) {
            int s0 = __shfl(sreg, g8 + u, 64);
            int s1 = __shfl(sreg, g8 + u + 1, 64);
            int s2 = __shfl(sreg, g8 + u + 2, 64);
            int s3 = __shfl(sreg, g8 + u + 3, 64);
            uint w0 = 0, w1 = 0, w2 = 0, w3 = 0;
            if (base + u < dg)     w0 = su[(s0 << 3) + c8];
            if (base + u + 1 < dg) w1 = su[(s1 << 3) + c8];
            if (base + u + 2 < dg) w2 = su[(s2 << 3) + c8];
            if (base + u + 3 < dg) w3 = su[(s3 << 3) + c8];
            s0f += lo16f(w0) + lo16f(w1) + lo16f(w2) + lo16f(w3);
            s1f += hi16f(w0) + hi16f(w1) + hi16f(w2) + hi16f(w3);
        }
    }
    a0 = s0f;
    a1 = s1f;
    dg_out = dg;
}

// ---------------- layer-1 gather (bf16: slice-major xT, shuffle-free) -----
// 4 slices x 16ch; cz=(bid%8)>>1 pins slice to an XCD pair. fp32 fallback:
// round-0 full-row gather over original x.
__global__ __launch_bounds__(256) void gather1_kernel(
    const void* __restrict__ x, const uint* __restrict__ xtu,
    const int* __restrict__ row_start, const int* __restrict__ csr_src,
    bf16* __restrict__ aggbuf, const int* __restrict__ flags) {
    int isbf = flags[0];
    int t = threadIdx.x;
    int lane = t & 63;
    int w = t >> 6;
    int bid = blockIdx.x;

    if (isbf) {
        int cz = (bid & 7) >> 1;                               // slice 0..3
        int wid = ((((bid >> 3) << 1) | (bid & 1)) << 2) + w;  // wave id in slice
        int nw = gridDim.x;                                    // waves per slice
        int g8 = lane & 0x38, c8 = lane & 7;                   // group base, chan-pair
        int g = lane >> 3;
        const uint* su = xtu + (long long)cz * (N_NODES * 8);  // slice as uint[N*8]
        uint* ag = (uint*)aggbuf;
        for (int oct = wid; oct < N_NODES / 8; oct += nw) {
            int nb0 = oct * 8;
            float a0, a1;
            int dg;
            slice_gather8(su, row_start, csr_src, nb0, g8, c8, lane, a0, a1, dg);
            float inv = 1.0f / fmaxf((float)dg, 1.0f);
            uint pk = (uint)f2bf_bits(a0 * inv) | ((uint)f2bf_bits(a1 * inv) << 16);
            // aggbuf[(nb0+g)*64 + cz*16 + 2*c8 .. +1] as uint
            ag[(nb0 + g) * 32 + cz * 8 + c8] = pk;
        }
    } else {
        // fp32 fallback: full-row gather over original x (round-0 code)
        int gw = (bid * 256 + t) >> 6;
        int nwv = (gridDim.x * 256) >> 6;
        int e4 = lane >> 4, q16 = lane & 15;
        const uint4* xf = (const uint4*)x;  // fp32 row = 16 uint4
        for (int p = gw; p * 2 < N_NODES; p += nwv) {
            int na = p * 2, nb = p * 2 + 1;
            int sa = row_start[na], ea = row_start[na + 1];
            int sb = row_start[nb], eb = row_start[nb + 1];
            int da = ea - sa, db = eb - sb;
            int maxd = max(da, db);
            float accA[4] = {0, 0, 0, 0};
            float accB[4] = {0, 0, 0, 0};
            for (int off = 0; off < maxd; off += 16) {
                int iA0 = sa + off + e4, iA1 = iA0 + 4, iA2 = iA0 + 8, iA3 = iA0 + 12;
                int iB0 = sb + off + e4, iB1 = iB0 + 4, iB2 = iB0 + 8, iB3 = iB0 + 12;
                int sA0 = (iA0 < ea) ? csr_src[iA0] : -1;
                int sA1 = (iA1 < ea) ? csr_src[iA1] : -1;
                int sA2 = (iA2 < ea) ? csr_src[iA2] : -1;
                int sA3 = (iA3 < ea) ? csr_src[iA3] : -1;
                int sB0 = (iB0 < eb) ? csr_src[iB0] : -1;
                int sB1 = (iB1 < eb) ? csr_src[iB1] : -1;
                int sB2 = (iB2 < eb) ? csr_src[iB2] : -1;
                int sB3 = (iB3 < eb) ? csr_src[iB3] : -1;
                uint4 vA0 = {0,0,0,0}, vA1 = {0,0,0,0}, vA2 = {0,0,0,0}, vA3 = {0,0,0,0};
                uint4 vB0 = {0,0,0,0}, vB1 = {0,0,0,0}, vB2 = {0,0,0,0}, vB3 = {0,0,0,0};
                if (sA0 >= 0) vA0 = xf[sA0 * 16 + q16];
                if (sA1 >= 0) vA1 = xf[sA1 * 16 + q16];
                if (sA2 >= 0) vA2 = xf[sA2 * 16 + q16];
                if (sA3 >= 0) vA3 = xf[sA3 * 16 + q16];
                if (sB0 >= 0) vB0 = xf[sB0 * 16 + q16];
                if (sB1 >= 0) vB1 = xf[sB1 * 16 + q16];
                if (sB2 >= 0) vB2 = xf[sB2 * 16 + q16];
                if (sB3 >= 0) vB3 = xf[sB3 * 16 + q16];
                ACCF4(accA, vA0, vA1)
                ACCF4(accA, vA2, vA3)
                ACCF4(accB, vB0, vB1)
                ACCF4(accB, vB2, vB3)
            }
#pragma unroll
            for (int m = 16; m <= 32; m <<= 1)
#pragma unroll
                for (int k = 0; k < 4; k++) {
                    accA[k] += __shfl_xor(accA[k], m, 64);
                    accB[k] += __shfl_xor(accB[k], m, 64);
                }
            float avA = 0.0f, avB = 0.0f;
#pragma unroll
            for (int k = 0; k < 4; k++) {
                float vA = __shfl(accA[k], lane >> 2, 64);
                float vB = __shfl(accB[k], lane >> 2, 64);
                avA = ((lane & 3) == k) ? vA : avA;
                avB = ((lane & 3) == k) ? vB : avB;
            }
            avA *= 1.0f / fmaxf((float)da, 1.0f);
            avB *= 1.0f / fmaxf((float)db, 1.0f);
            aggbuf[(long long)na * 64 + lane] = __float2bfloat16(avA);
            aggbuf[(long long)nb * 64 + lane] = __float2bfloat16(avB);
        }
    }
}

// ---------------- layer-1+2 GEMMs (MFMA, dense coalesced staging) ----------------
// Writes z/r slice-major: zbufT[2][N][16], rbufT[2][N][16] (for node2's L2 slicing).
__global__ __launch_bounds__(256) void gemm1_kernel(
    const void* __restrict__ x, const bf16* __restrict__ aggbuf,
    const void* __restrict__ W1l, const void* __restrict__ b1l,
    const void* __restrict__ W1r, const void* __restrict__ W2l,
    const void* __restrict__ b2l, const void* __restrict__ W2r,
    bf16* __restrict__ zbufT, bf16* __restrict__ rbufT,
    const int* __restrict__ flags) {
    __shared__ __align__(16) unsigned short sW1t[64][136];
    __shared__ __align__(16) unsigned short sA[64][136];
    __shared__ __align__(16) unsigned short sW2t[64][72];
    __shared__ __align__(16) unsigned short sH[64][72];
    __shared__ float sB1[64];
    __shared__ float sB2[32];

    int isbf = flags[0];
    int t = threadIdx.x;
    int n0 = blockIdx.x * 64;

    for (int i = t; i < 64 * 128; i += 256) {
        int n = i & 63, k = i >> 6;
        unsigned short v;
        if (isbf)
            v = (k < 64) ? ((const unsigned short*)W1l)[k * 64 + n]
                         : ((const unsigned short*)W1r)[(k - 64) * 64 + n];
        else
            v = f2bits((k < 64) ? ((const float*)W1l)[k * 64 + n]
                                : ((const float*)W1r)[(k - 64) * 64 + n]);
        sW1t[n][k] = v;
    }
    for (int i = t; i < 64 * 64; i += 256) {
        int n = i & 63, k = i >> 6;
        unsigned short v;
        if (isbf)
            v = (n < 32) ? ((const unsigned short*)W2l)[k * 32 + n]
                         : ((const unsigned short*)W2r)[k * 32 + (n - 32)];
        else
            v = f2bits((n < 32) ? ((const float*)W2l)[k * 32 + n]
                                : ((const float*)W2r)[k * 32 + (n - 32)]);
        sW2t[n][k] = v;
    }
    if (t < 64) sB1[t] = get_f(b1l, t, isbf);
    if (t < 32) sB2[t] = get_f(b2l, t, isbf);

    const uint4* ag4 = (const uint4*)aggbuf;
    if (isbf) {
        const uint4* x4 = (const uint4*)x;
        for (int i = t; i < 64 * 16; i += 256) {
            int m = i >> 4, c = i & 15;
            int nn = min(n0 + m, N_NODES - 1);
            uint4 v = (c < 8) ? ag4[(long long)nn * 8 + c]
                              : x4[(long long)nn * 8 + (c - 8)];
            *(uint4*)&sA[m][c * 8] = v;
        }
    } else {
        for (int i = t; i < 64 * 8; i += 256) {
            int m = i >> 3, c = i & 7;
            int nn = min(n0 + m, N_NODES - 1);
            *(uint4*)&sA[m][c * 8] = ag4[(long long)nn * 8 + c];
        }
        const float* xf = (const float*)x;
        for (int i = t; i < 64 * 64; i += 256) {
            int m = i >> 6, c = i & 63;
            int nn = min(n0 + m, N_NODES - 1);
            sA[m][64 + c] = f2bf_bits(xf[(long long)nn * 64 + c]);
        }
    }
    __syncthreads();

    int w = t >> 6, lane = t & 63;
    int mbase = w * 16;
    int q = lane >> 4, r15 = lane & 15;
    f32x4 acc1[4] = {{0,0,0,0},{0,0,0,0},{0,0,0,0},{0,0,0,0}};
#pragma unroll
    for (int ks = 0; ks < 4; ks++) {
        bf16x8 afrag = *(const bf16x8*)&sA[mbase + r15][ks * 32 + q * 8];
#pragma unroll
        for (int nt = 0; nt < 4; nt++) {
            bf16x8 bfrag = *(const bf16x8*)&sW1t[nt * 16 + r15][ks * 32 + q * 8];
            acc1[nt] = __builtin_amdgcn_mfma_f32_16x16x32_bf16(afrag, bfrag, acc1[nt], 0, 0, 0);
        }
    }
#pragma unroll
    for (int nt = 0; nt < 4; nt++) {
        int col = nt * 16 + r15;
        float bias = sB1[col];
#pragma unroll
        for (int rr = 0; rr < 4; rr++) {
            int m = mbase + q * 4 + rr;
            sH[m][col] = f2bf_bits(fmaxf(acc1[nt][rr] + bias, 0.0f));
        }
    }
    __syncthreads();

    f32x4 acc2[4] = {{0,0,0,0},{0,0,0,0},{0,0,0,0},{0,0,0,0}};
#pragma unroll
    for (int ks = 0; ks < 2; ks++) {
        bf16x8 afrag = *(const bf16x8*)&sH[mbase + r15][ks * 32 + q * 8];
#pragma unroll
        for (int nt = 0; nt < 4; nt++) {
            bf16x8 bfrag = *(const bf16x8*)&sW2t[nt * 16 + r15][ks * 32 + q * 8];
            acc2[nt] = __builtin_amdgcn_mfma_f32_16x16x32_bf16(afrag, bfrag, acc2[nt], 0, 0, 0);
        }
    }
#pragma unroll
    for (int nt = 0; nt < 4; nt++) {
        int col = nt * 16 + r15;
#pragma unroll
        for (int rr = 0; rr < 4; rr++) {
            int m = mbase + q * 4 + rr;
            int n = n0 + m;
            if (n < N_NODES) {
                float v = acc2[nt][rr];
                if (col < 32) {
                    zbufT[(long long)(col >> 4) * (N_NODES * 16) +
                          (long long)n * 16 + (col & 15)] = __float2bfloat16(v);
                } else {
                    int c2 = col - 32;
                    rbufT[(long long)(c2 >> 4) * (N_NODES * 16) +
                          (long long)n * 16 + (c2 & 15)] =
                        __float2bfloat16(v + sB2[c2]);
                }
            }
        }
    }
}

// ---------------- layer-2: gather z (slice-major, shuffle-free) -----------
// 2 slices x 16ch; cz=(bid%8)>>2 pins slice to 4 XCDs.
__global__ __launch_bounds__(256) void node2_kernel(
    const int* __restrict__ row_start, const int* __restrict__ csr_src,
    const uint* __restrict__ zTu, const bf16* __restrict__ rbufT,
    void* __restrict__ out, const int* __restrict__ flags) {
    int isbf = flags[0];
    int t = threadIdx.x;
    int lane = t & 63;
    int w = t >> 6;
    int bid = blockIdx.x;
    int cz = (bid & 7) >> 2;                                   // slice 0..1
    int wid = ((((bid >> 3) << 2) | (bid & 3)) << 2) + w;      // wave id within cz
    int nw = gridDim.x * 2;                                    // waves per cz
    int g8 = lane & 0x38, c8 = lane & 7;
    int g = lane >> 3;
    const uint* su = zTu + (long long)cz * (N_NODES * 8);
    const uint* ru = (const uint*)(rbufT + (long long)cz * (N_NODES * 16));

    for (int oct = wid; oct < N_NODES / 8; oct += nw) {
        int nb0 = oct * 8;
        float a0, a1;
        int dg;
        slice_gather8(su, row_start, csr_src, nb0, g8, c8, lane, a0, a1, dg);
        float inv = 1.0f / fmaxf((float)dg, 1.0f);
        int n = nb0 + g;
        uint rb = ru[n * 8 + c8];
        float r0 = a0 * inv + lo16f(rb);
        float r1 = a1 * inv + hi16f(rb);
        if (isbf) {
            uint pk = (uint)f2bf_bits(r0) | ((uint)f2bf_bits(r1) << 16);
            ((uint*)out)[n * 16 + cz * 8 + c8] = pk;
        } else {
            ((float*)out)[(long long)n * 32 + cz * 16 + 2 * c8] = r0;
            ((float*)out)[(long long)n * 32 + cz * 16 + 2 * c8 + 1] = r1;
        }
    }
}

extern "C" void kernel_launch(void* const* d_in, const int* in_sizes, int n_in,
                              void* d_out, int out_size, void* d_ws, size_t ws_size,
                              hipStream_t stream) {
    const void* x = d_in[0];
    const void* ei = d_in[1];  // [2, E]: src = [0,E), dst = [E,2E)
    const void* W1l = d_in[2];
    const void* b1l = d_in[3];
    const void* W1r = d_in[4];
    const void* W2l = d_in[5];
    const void* b2l = d_in[6];
    const void* W2r = d_in[7];

    // workspace layout (~42 MB), triple-aliased across pipeline phases:
    //   [0, 16.0MB)      bucket_data (dead after csrB)  / aggbuf (gather1->gemm1)
    //   [29.2, 42.0MB)   xT (transpose->gather1, bf16)  / zbufT+rbufT (gemm1->node2)
    char* ws = (char*)d_ws;
    uint* bucket_data = (uint*)ws;                    // NBKT*BKT_CAP u32 = 16.0 MB
    bf16* aggbuf = (bf16*)ws;                         // N*64 bf16 = 12.8 MB (alias)
    int* csr_src = (int*)(ws + 16015424);             // E i32 = 12.8 MB
    int* row_start = (int*)(ws + 28815424);           // N+1 i32
    int* bucket_cursor = (int*)(ws + 29215488);       // NBKT i32
    int* bucket_base = (int*)(ws + 29217088);         // NBKT i32
    uint* xtu = (uint*)(ws + 29218688);               // 4*N*16 bf16 = 12.8 MB (alias)
    bf16* zbufT = (bf16*)(ws + 29218688);             // 2*N*16 bf16 = 6.4 MB
    bf16* rbufT = (bf16*)(ws + 35618688);             // 2*N*16 bf16 = 6.4 MB
    int* flags = (int*)(ws + 42018688);               // 2 i32

    hipMemsetAsync(bucket_cursor, 0, NBKT * 4, stream);

    detect_kernel<<<1, 64, 0, stream>>>(x, ei, flags);
    transpose_kernel<<<1563, 256, 0, stream>>>(x, (uint4*)xtu, flags);
    scatterA_kernel<<<NBKT, 256, 0, stream>>>(ei, bucket_cursor, bucket_data, flags);
    scanBuckets_kernel<<<1, 512, 0, stream>>>(bucket_cursor, bucket_base);
    csrB_kernel<<<NBKT, 256, 0, stream>>>(bucket_cursor, bucket_base, bucket_data,
                                          csr_src, row_start);
    gather1_kernel<<<4096, 256, 0, stream>>>(x, xtu, row_start, csr_src, aggbuf,
                                             flags);
    gemm1_kernel<<<1563, 256, 0, stream>>>(x, aggbuf, W1l, b1l, W1r, W2l, b2l,
                                           W2r, zbufT, rbufT, flags);
    node2_kernel<<<4096, 256, 0, stream>>>(row_start, csr_src, (const uint*)zbufT,
                                           rbufT, d_out, flags);
}

// Round 4
// 366.134 us; speedup vs baseline: 1.3289x; 1.0226x over previous
//
#include <hip/hip_runtime.h>
#include <hip/hip_bf16.h>

#define N_NODES 100000
#define N_EDGES 3200000
#define NBKT 391      // ceil(N_NODES/256): bucket = dst>>8
#define BKT_CAP 10240 // avg 8184 edges/bucket, +23 sigma margin
#define NOCT (N_NODES / 8)

typedef __hip_bfloat16 bf16;
typedef unsigned int uint;
typedef __attribute__((ext_vector_type(8))) short bf16x8;
typedef __attribute__((ext_vector_type(4))) float f32x4;

__device__ __forceinline__ float b2f(bf16 v) { return __bfloat162float(v); }

__device__ __forceinline__ float bits2f(unsigned short w) {
    union { unsigned short u; bf16 b; } c;
    c.u = w;
    return __bfloat162float(c.b);
}
__device__ __forceinline__ unsigned short f2bits(float f) {  // truncate
    return (unsigned short)(__float_as_uint(f) >> 16);
}
__device__ __forceinline__ unsigned short f2bf_bits(float f) {  // RNE
    bf16 b = __float2bfloat16(f);
    unsigned short u;
    __builtin_memcpy(&u, &b, 2);
    return u;
}
__device__ __forceinline__ float lo16f(uint w) { return __uint_as_float(w << 16); }
__device__ __forceinline__ float hi16f(uint w) { return __uint_as_float(w & 0xffff0000u); }

// physical XCD id (HW-verified on MI355X: returns 0..7). hwreg 20 = HW_REG_XCC_ID.
__device__ __forceinline__ int get_xcd() {
    uint v;
    asm volatile("s_getreg_b32 %0, hwreg(20, 0, 32)" : "=s"(v));
    return (int)(v & 7);
}

// runtime dtype accessors -------------------------------------------------
__device__ __forceinline__ int get_idx(const void* ei, long long pos, int is64) {
    if (is64) return (int)((const long long*)ei)[pos];
    return ((const int*)ei)[pos];
}
__device__ __forceinline__ float get_f(const void* p, long long pos, int isbf) {
    if (isbf) return b2f(((const bf16*)p)[pos]);
    return ((const float*)p)[pos];
}

// ---------------- dtype detection (1 wave) ----------------
__global__ void detect_kernel(const void* __restrict__ x,
                              const void* __restrict__ ei,
                              int* __restrict__ flags) {
    int lane = threadIdx.x;  // 64 threads
    const unsigned short* xw = (const unsigned short*)x;
    float v = bits2f(xw[2 * lane]);
    bool plaus = (v == v) && fabsf(v) > 1e-3f && fabsf(v) < 1e2f;
    unsigned long long m1 = __ballot(plaus);
    const int* iw = (const int*)ei;
    bool z = (iw[2 * lane + 1] == 0);
    unsigned long long m2 = __ballot(z);
    if (lane == 0) {
        flags[0] = (__popcll(m1) >= 32) ? 1 : 0;
        flags[1] = (__popcll(m2) == 64) ? 1 : 0;
    }
}

// ---------------- transpose x -> slice-major xT[4][N][16] (bf16 only) -----
// Each 16-ch slice = 3.2 MB CONTIGUOUS (per-XCD-L2-resident; full-line use).
__global__ __launch_bounds__(256) void transpose_kernel(
    const void* __restrict__ x, uint4* __restrict__ xt,
    const int* __restrict__ flags) {
    if (!flags[0]) return;  // fp32 path uses original layout
    int i = blockIdx.x * 256 + threadIdx.x;  // N*4 chunks of 32B
    if (i >= N_NODES * 4) return;
    int node = i >> 2, cz = i & 3;
    const uint4* x4 = (const uint4*)x;
    uint4 a = x4[(long long)node * 8 + cz * 2];
    uint4 b = x4[(long long)node * 8 + cz * 2 + 1];
    long long o = (long long)cz * (N_NODES * 2) + (long long)node * 2;
    xt[o] = a;
    xt[o + 1] = b;
}

// ---------------- pass A: bucket edges by dst>>8 ----------------
__global__ __launch_bounds__(256) void scatterA_kernel(
    const void* __restrict__ ei, int* __restrict__ bucket_cursor,
    uint* __restrict__ bucket_data, const int* __restrict__ flags) {
    __shared__ int lhist[NBKT];
    __shared__ int lbase[NBKT];
    int is64 = flags[1];
    int t = threadIdx.x;
    int chunk0 = blockIdx.x * 8192;
    int dreg[32];

    for (int i = t; i < NBKT; i += 256) lhist[i] = 0;
    __syncthreads();
#pragma unroll
    for (int j = 0; j < 32; j++) {
        int e = chunk0 + j * 256 + t;
        int d = -1;
        if (e < N_EDGES) {
            d = get_idx(ei, (long long)N_EDGES + e, is64);
            atomicAdd(&lhist[d >> 8], 1);
        }
        dreg[j] = d;
    }
    __syncthreads();
    for (int i = t; i < NBKT; i += 256) {
        int c = lhist[i];
        lbase[i] = c ? atomicAdd(&bucket_cursor[i], c) : 0;
        lhist[i] = 0;  // reuse as local cursor
    }
    __syncthreads();
#pragma unroll
    for (int j = 0; j < 32; j++) {
        int e = chunk0 + j * 256 + t;
        int d = dreg[j];
        if (d >= 0) {
            int s = get_idx(ei, e, is64);
            int b = d >> 8;
            int o = lbase[b] + atomicAdd(&lhist[b], 1);
            if (o < BKT_CAP)
                bucket_data[(long long)b * BKT_CAP + o] = ((uint)(d & 255) << 17) | (uint)s;
        }
    }
}

// ---------------- scan bucket counts -> bucket base ----------------
__global__ void scanBuckets_kernel(const int* __restrict__ cnt,
                                   int* __restrict__ base) {
    __shared__ int buf[512];
    int t = threadIdx.x;  // 512 threads
    int v = (t < NBKT) ? cnt[t] : 0;
    buf[t] = v;
    __syncthreads();
    for (int off = 1; off < 512; off <<= 1) {
        int add = (t >= off) ? buf[t - off] : 0;
        __syncthreads();
        buf[t] += add;
        __syncthreads();
    }
    if (t < NBKT) base[t] = buf[t] - v;  // exclusive
}

// ---------------- pass B: per-bucket CSR build ----------------
__global__ __launch_bounds__(256) void csrB_kernel(
    const int* __restrict__ bucket_cnt, const int* __restrict__ bucket_base,
    const uint* __restrict__ bucket_data, int* __restrict__ csr_src,
    int* __restrict__ row_start) {
    __shared__ int lh[256];
    __shared__ int buf[256];
    int b = blockIdx.x;
    int t = threadIdx.x;
    int cnt = bucket_cnt[b];
    if (cnt > BKT_CAP) cnt = BKT_CAP;
    int base = bucket_base[b];
    const uint* bd = bucket_data + (long long)b * BKT_CAP;

    lh[t] = 0;
    __syncthreads();
    for (int i = t; i < cnt; i += 256) atomicAdd(&lh[bd[i] >> 17], 1);
    __syncthreads();
    int v = lh[t];
    buf[t] = v;
    __syncthreads();
    for (int off = 1; off < 256; off <<= 1) {
        int add = (t >= off) ? buf[t - off] : 0;
        __syncthreads();
        buf[t] += add;
        __syncthreads();
    }
    int excl = buf[t] - v;
    int g = (b << 8) + t;
    if (g < N_NODES) row_start[g] = base + excl;
    lh[t] = excl;  // reuse as local cursor
    __syncthreads();
    for (int i = t; i < cnt; i += 256) {
        uint e = bd[i];
        int o = atomicAdd(&lh[e >> 17], 1);
        csr_src[base + o] = (int)(e & 0x1FFFFu);
    }
    if (b == 0 && t == 0) row_start[N_NODES] = N_EDGES;
}

#define ACCF4(acc, v, v2)                                                        \
    acc[0] += __uint_as_float((v).x) + __uint_as_float((v2).x);                   \
    acc[1] += __uint_as_float((v).y) + __uint_as_float((v2).y);                   \
    acc[2] += __uint_as_float((v).z) + __uint_as_float((v2).z);                   \
    acc[3] += __uint_as_float((v).w) + __uint_as_float((v2).w);

// ---- shared slice-gather core: 8 nodes/wave, 8 lanes/node, 2ch/lane ------
// slice = [N][16] bf16 viewed as uint[N*8]. In-lane accumulation: NO
// reduction shuffles; one src-broadcast shuffle per edge.
__device__ __forceinline__ void slice_gather8(
    const uint* __restrict__ su, const int* __restrict__ row_start,
    const int* __restrict__ csr_src, int nb0, int g8, int c8, int lane,
    float& a0, float& a1, int& dg_out) {
    // lanes 0..8 load row_start[nb0+l]; groups read their own bounds
    int rl = (lane <= 8) ? row_start[nb0 + lane] : 0;
    int sg = __shfl(rl, g8 >> 3, 64);
    int eg = __shfl(rl, (g8 >> 3) + 1, 64);
    int dg = eg - sg;
    // wave-uniform maxd: groups g^1,g^2,g^4 live at lane^8,^16,^32
    int maxd = dg;
    maxd = max(maxd, __shfl_xor(maxd, 8, 64));
    maxd = max(maxd, __shfl_xor(maxd, 16, 64));
    maxd = max(maxd, __shfl_xor(maxd, 32, 64));

    float s0f = 0.0f, s1f = 0.0f;
    for (int base = 0; base < maxd; base += 8) {
        int pf = sg + base + c8;
        int sreg = (pf < eg) ? csr_src[pf] : 0;
#pragma unroll
        for (int u = 0; u < 8; u += 4) {
            int s0 = __shfl(sreg, g8 + u, 64);
            int s1 = __shfl(sreg, g8 + u + 1, 64);
            int s2 = __shfl(sreg, g8 + u + 2, 64);
            int s3 = __shfl(sreg, g8 + u + 3, 64);
            uint w0 = 0, w1 = 0, w2 = 0, w3 = 0;
            if (base + u < dg)     w0 = su[(s0 << 3) + c8];
            if (base + u + 1 < dg) w1 = su[(s1 << 3) + c8];
            if (base + u + 2 < dg) w2 = su[(s2 << 3) + c8];
            if (base + u + 3 < dg) w3 = su[(s3 << 3) + c8];
            s0f += lo16f(w0) + lo16f(w1) + lo16f(w2) + lo16f(w3);
            s1f += hi16f(w0) + hi16f(w1) + hi16f(w2) + hi16f(w3);
        }
    }
    a0 = s0f;
    a1 = s1f;
    dg_out = dg;
}

// ---------------- layer-1 gather (bf16: slice-major xT, XCD-exact) --------
// 4 slices x 16ch. Slice is chosen from the PHYSICAL XCD id (getreg) ->
// pinning holds regardless of block-dispatch policy. Work comes from a
// per-slice atomic queue; after a slice drains, blocks steal from the other
// slices (correctness never depends on getreg/dispatch behavior).
__global__ __launch_bounds__(256) void gather1_kernel(
    const void* __restrict__ x, const uint* __restrict__ xtu,
    const int* __restrict__ row_start, const int* __restrict__ csr_src,
    bf16* __restrict__ aggbuf, int* __restrict__ gcursor,
    const int* __restrict__ flags) {
    int isbf = flags[0];
    int t = threadIdx.x;
    int lane = t & 63;
    int bid = blockIdx.x;

    if (isbf) {
        int g8 = lane & 0x38, c8 = lane & 7;  // group base, chan-pair
        int g = lane >> 3;
        int cz0 = (get_xcd() >> 1) & 3;       // this XCD pair's slice
        uint* ag = (uint*)aggbuf;
        for (int k = 0; k < 4; k++) {
            int cz = (cz0 + k) & 3;
            const uint* su = xtu + (long long)cz * (N_NODES * 8);
            while (true) {
                int oct = 0;
                if (lane == 0) oct = atomicAdd(&gcursor[cz], 1);
                oct = __shfl(oct, 0, 64);
                if (oct >= NOCT) break;
                int nb0 = oct * 8;
                float a0, a1;
                int dg;
                slice_gather8(su, row_start, csr_src, nb0, g8, c8, lane,
                              a0, a1, dg);
                float inv = 1.0f / fmaxf((float)dg, 1.0f);
                uint pk = (uint)f2bf_bits(a0 * inv) |
                          ((uint)f2bf_bits(a1 * inv) << 16);
                ag[(nb0 + g) * 32 + cz * 8 + c8] = pk;
            }
        }
    } else {
        // fp32 fallback: full-row gather over original x (round-0 code)
        int gw = (bid * 256 + t) >> 6;
        int nwv = (gridDim.x * 256) >> 6;
        int e4 = lane >> 4, q16 = lane & 15;
        const uint4* xf = (const uint4*)x;  // fp32 row = 16 uint4
        for (int p = gw; p * 2 < N_NODES; p += nwv) {
            int na = p * 2, nb = p * 2 + 1;
            int sa = row_start[na], ea = row_start[na + 1];
            int sb = row_start[nb], eb = row_start[nb + 1];
            int da = ea - sa, db = eb - sb;
            int maxd = max(da, db);
            float accA[4] = {0, 0, 0, 0};
            float accB[4] = {0, 0, 0, 0};
            for (int off = 0; off < maxd; off += 16) {
                int iA0 = sa + off + e4, iA1 = iA0 + 4, iA2 = iA0 + 8, iA3 = iA0 + 12;
                int iB0 = sb + off + e4, iB1 = iB0 + 4, iB2 = iB0 + 8, iB3 = iB0 + 12;
                int sA0 = (iA0 < ea) ? csr_src[iA0] : -1;
                int sA1 = (iA1 < ea) ? csr_src[iA1] : -1;
                int sA2 = (iA2 < ea) ? csr_src[iA2] : -1;
                int sA3 = (iA3 < ea) ? csr_src[iA3] : -1;
                int sB0 = (iB0 < eb) ? csr_src[iB0] : -1;
                int sB1 = (iB1 < eb) ? csr_src[iB1] : -1;
                int sB2 = (iB2 < eb) ? csr_src[iB2] : -1;
                int sB3 = (iB3 < eb) ? csr_src[iB3] : -1;
                uint4 vA0 = {0,0,0,0}, vA1 = {0,0,0,0}, vA2 = {0,0,0,0}, vA3 = {0,0,0,0};
                uint4 vB0 = {0,0,0,0}, vB1 = {0,0,0,0}, vB2 = {0,0,0,0}, vB3 = {0,0,0,0};
                if (sA0 >= 0) vA0 = xf[sA0 * 16 + q16];
                if (sA1 >= 0) vA1 = xf[sA1 * 16 + q16];
                if (sA2 >= 0) vA2 = xf[sA2 * 16 + q16];
                if (sA3 >= 0) vA3 = xf[sA3 * 16 + q16];
                if (sB0 >= 0) vB0 = xf[sB0 * 16 + q16];
                if (sB1 >= 0) vB1 = xf[sB1 * 16 + q16];
                if (sB2 >= 0) vB2 = xf[sB2 * 16 + q16];
                if (sB3 >= 0) vB3 = xf[sB3 * 16 + q16];
                ACCF4(accA, vA0, vA1)
                ACCF4(accA, vA2, vA3)
                ACCF4(accB, vB0, vB1)
                ACCF4(accB, vB2, vB3)
            }
#pragma unroll
            for (int m = 16; m <= 32; m <<= 1)
#pragma unroll
                for (int k = 0; k < 4; k++) {
                    accA[k] += __shfl_xor(accA[k], m, 64);
                    accB[k] += __shfl_xor(accB[k], m, 64);
                }
            float avA = 0.0f, avB = 0.0f;
#pragma unroll
            for (int k = 0; k < 4; k++) {
                float vA = __shfl(accA[k], lane >> 2, 64);
                float vB = __shfl(accB[k], lane >> 2, 64);
                avA = ((lane & 3) == k) ? vA : avA;
                avB = ((lane & 3) == k) ? vB : avB;
            }
            avA *= 1.0f / fmaxf((float)da, 1.0f);
            avB *= 1.0f / fmaxf((float)db, 1.0f);
            aggbuf[(long long)na * 64 + lane] = __float2bfloat16(avA);
            aggbuf[(long long)nb * 64 + lane] = __float2bfloat16(avB);
        }
    }
}

// ---------------- layer-1+2 GEMMs (MFMA, dense coalesced staging) ----------------
// Writes z/r slice-major: zbufT[2][N][16], rbufT[2][N][16] (for node2's L2 slicing).
__global__ __launch_bounds__(256) void gemm1_kernel(
    const void* __restrict__ x, const bf16* __restrict__ aggbuf,
    const void* __restrict__ W1l, const void* __restrict__ b1l,
    const void* __restrict__ W1r, const void* __restrict__ W2l,
    const void* __restrict__ b2l, const void* __restrict__ W2r,
    bf16* __restrict__ zbufT, bf16* __restrict__ rbufT,
    const int* __restrict__ flags) {
    __shared__ __align__(16) unsigned short sW1t[64][136];
    __shared__ __align__(16) unsigned short sA[64][136];
    __shared__ __align__(16) unsigned short sW2t[64][72];
    __shared__ __align__(16) unsigned short sH[64][72];
    __shared__ float sB1[64];
    __shared__ float sB2[32];

    int isbf = flags[0];
    int t = threadIdx.x;
    int n0 = blockIdx.x * 64;

    for (int i = t; i < 64 * 128; i += 256) {
        int n = i & 63, k = i >> 6;
        unsigned short v;
        if (isbf)
            v = (k < 64) ? ((const unsigned short*)W1l)[k * 64 + n]
                         : ((const unsigned short*)W1r)[(k - 64) * 64 + n];
        else
            v = f2bits((k < 64) ? ((const float*)W1l)[k * 64 + n]
                                : ((const float*)W1r)[(k - 64) * 64 + n]);
        sW1t[n][k] = v;
    }
    for (int i = t; i < 64 * 64; i += 256) {
        int n = i & 63, k = i >> 6;
        unsigned short v;
        if (isbf)
            v = (n < 32) ? ((const unsigned short*)W2l)[k * 32 + n]
                         : ((const unsigned short*)W2r)[k * 32 + (n - 32)];
        else
            v = f2bits((n < 32) ? ((const float*)W2l)[k * 32 + n]
                                : ((const float*)W2r)[k * 32 + (n - 32)]);
        sW2t[n][k] = v;
    }
    if (t < 64) sB1[t] = get_f(b1l, t, isbf);
    if (t < 32) sB2[t] = get_f(b2l, t, isbf);

    const uint4* ag4 = (const uint4*)aggbuf;
    if (isbf) {
        const uint4* x4 = (const uint4*)x;
        for (int i = t; i < 64 * 16; i += 256) {
            int m = i >> 4, c = i & 15;
            int nn = min(n0 + m, N_NODES - 1);
            uint4 v = (c < 8) ? ag4[(long long)nn * 8 + c]
                              : x4[(long long)nn * 8 + (c - 8)];
            *(uint4*)&sA[m][c * 8] = v;
        }
    } else {
        for (int i = t; i < 64 * 8; i += 256) {
            int m = i >> 3, c = i & 7;
            int nn = min(n0 + m, N_NODES - 1);
            *(uint4*)&sA[m][c * 8] = ag4[(long long)nn * 8 + c];
        }
        const float* xf = (const float*)x;
        for (int i = t; i < 64 * 64; i += 256) {
            int m = i >> 6, c = i & 63;
            int nn = min(n0 + m, N_NODES - 1);
            sA[m][64 + c] = f2bf_bits(xf[(long long)nn * 64 + c]);
        }
    }
    __syncthreads();

    int w = t >> 6, lane = t & 63;
    int mbase = w * 16;
    int q = lane >> 4, r15 = lane & 15;
    f32x4 acc1[4] = {{0,0,0,0},{0,0,0,0},{0,0,0,0},{0,0,0,0}};
#pragma unroll
    for (int ks = 0; ks < 4; ks++) {
        bf16x8 afrag = *(const bf16x8*)&sA[mbase + r15][ks * 32 + q * 8];
#pragma unroll
        for (int nt = 0; nt < 4; nt++) {
            bf16x8 bfrag = *(const bf16x8*)&sW1t[nt * 16 + r15][ks * 32 + q * 8];
            acc1[nt] = __builtin_amdgcn_mfma_f32_16x16x32_bf16(afrag, bfrag, acc1[nt], 0, 0, 0);
        }
    }
#pragma unroll
    for (int nt = 0; nt < 4; nt++) {
        int col = nt * 16 + r15;
        float bias = sB1[col];
#pragma unroll
        for (int rr = 0; rr < 4; rr++) {
            int m = mbase + q * 4 + rr;
            sH[m][col] = f2bf_bits(fmaxf(acc1[nt][rr] + bias, 0.0f));
        }
    }
    __syncthreads();

    f32x4 acc2[4] = {{0,0,0,0},{0,0,0,0},{0,0,0,0},{0,0,0,0}};
#pragma unroll
    for (int ks = 0; ks < 2; ks++) {
        bf16x8 afrag = *(const bf16x8*)&sH[mbase + r15][ks * 32 + q * 8];
#pragma unroll
        for (int nt = 0; nt < 4; nt++) {
            bf16x8 bfrag = *(const bf16x8*)&sW2t[nt * 16 + r15][ks * 32 + q * 8];
            acc2[nt] = __builtin_amdgcn_mfma_f32_16x16x32_bf16(afrag, bfrag, acc2[nt], 0, 0, 0);
        }
    }
#pragma unroll
    for (int nt = 0; nt < 4; nt++) {
        int col = nt * 16 + r15;
#pragma unroll
        for (int rr = 0; rr < 4; rr++) {
            int m = mbase + q * 4 + rr;
            int n = n0 + m;
            if (n < N_NODES) {
                float v = acc2[nt][rr];
                if (col < 32) {
                    zbufT[(long long)(col >> 4) * (N_NODES * 16) +
                          (long long)n * 16 + (col & 15)] = __float2bfloat16(v);
                } else {
                    int c2 = col - 32;
                    rbufT[(long long)(c2 >> 4) * (N_NODES * 16) +
                          (long long)n * 16 + (c2 & 15)] =
                        __float2bfloat16(v + sB2[c2]);
                }
            }
        }
    }
}

// ---------------- layer-2: gather z (slice-major, shuffle-free) -----------
// 2 slices x 16ch; cz=(bid%8)>>2 pins slice (empirically verified: 37MB
// FETCH in round 2 -> residency works for this mapping; do not touch).
__global__ __launch_bounds__(256) void node2_kernel(
    const int* __restrict__ row_start, const int* __restrict__ csr_src,
    const uint* __restrict__ zTu, const bf16* __restrict__ rbufT,
    void* __restrict__ out, const int* __restrict__ flags) {
    int isbf = flags[0];
    int t = threadIdx.x;
    int lane = t & 63;
    int w = t >> 6;
    int bid = blockIdx.x;
    int cz = (bid & 7) >> 2;                                   // slice 0..1
    int wid = ((((bid >> 3) << 2) | (bid & 3)) << 2) + w;      // wave id within cz
    int nw = gridDim.x * 2;                                    // waves per cz
    int g8 = lane & 0x38, c8 = lane & 7;
    int g = lane >> 3;
    const uint* su = zTu + (long long)cz * (N_NODES * 8);
    const uint* ru = (const uint*)(rbufT + (long long)cz * (N_NODES * 16));

    for (int oct = wid; oct < NOCT; oct += nw) {
        int nb0 = oct * 8;
        float a0, a1;
        int dg;
        slice_gather8(su, row_start, csr_src, nb0, g8, c8, lane, a0, a1, dg);
        float inv = 1.0f / fmaxf((float)dg, 1.0f);
        int n = nb0 + g;
        uint rb = ru[n * 8 + c8];
        float r0 = a0 * inv + lo16f(rb);
        float r1 = a1 * inv + hi16f(rb);
        if (isbf) {
            uint pk = (uint)f2bf_bits(r0) | ((uint)f2bf_bits(r1) << 16);
            ((uint*)out)[n * 16 + cz * 8 + c8] = pk;
        } else {
            ((float*)out)[(long long)n * 32 + cz * 16 + 2 * c8] = r0;
            ((float*)out)[(long long)n * 32 + cz * 16 + 2 * c8 + 1] = r1;
        }
    }
}

extern "C" void kernel_launch(void* const* d_in, const int* in_sizes, int n_in,
                              void* d_out, int out_size, void* d_ws, size_t ws_size,
                              hipStream_t stream) {
    const void* x = d_in[0];
    const void* ei = d_in[1];  // [2, E]: src = [0,E), dst = [E,2E)
    const void* W1l = d_in[2];
    const void* b1l = d_in[3];
    const void* W1r = d_in[4];
    const void* W2l = d_in[5];
    const void* b2l = d_in[6];
    const void* W2r = d_in[7];

    // workspace layout (~42 MB), triple-aliased across pipeline phases:
    //   [0, 16.0MB)      bucket_data (dead after csrB)  / aggbuf (gather1->gemm1)
    //   [29.2, 42.0MB)   xT (transpose->gather1, bf16)  / zbufT+rbufT (gemm1->node2)
    char* ws = (char*)d_ws;
    uint* bucket_data = (uint*)ws;                    // NBKT*BKT_CAP u32 = 16.0 MB
    bf16* aggbuf = (bf16*)ws;                         // N*64 bf16 = 12.8 MB (alias)
    int* csr_src = (int*)(ws + 16015424);             // E i32 = 12.8 MB
    int* row_start = (int*)(ws + 28815424);           // N+1 i32
    int* bucket_cursor = (int*)(ws + 29215488);       // NBKT i32
    int* bucket_base = (int*)(ws + 29217088);         // NBKT i32
    uint* xtu = (uint*)(ws + 29218688);               // 4*N*16 bf16 = 12.8 MB (alias)
    bf16* zbufT = (bf16*)(ws + 29218688);             // 2*N*16 bf16 = 6.4 MB
    bf16* rbufT = (bf16*)(ws + 35618688);             // 2*N*16 bf16 = 6.4 MB
    int* flags = (int*)(ws + 42018688);               // 2 i32
    int* gcursor = (int*)(ws + 42018696);             // 4 i32 slice queues

    hipMemsetAsync(bucket_cursor, 0, NBKT * 4, stream);
    hipMemsetAsync(gcursor, 0, 16, stream);

    detect_kernel<<<1, 64, 0, stream>>>(x, ei, flags);
    transpose_kernel<<<1563, 256, 0, stream>>>(x, (uint4*)xtu, flags);
    scatterA_kernel<<<NBKT, 256, 0, stream>>>(ei, bucket_cursor, bucket_data, flags);
    scanBuckets_kernel<<<1, 512, 0, stream>>>(bucket_cursor, bucket_base);
    csrB_kernel<<<NBKT, 256, 0, stream>>>(bucket_cursor, bucket_base, bucket_data,
                                          csr_src, row_start);
    gather1_kernel<<<4096, 256, 0, stream>>>(x, xtu, row_start, csr_src, aggbuf,
                                             gcursor, flags);
    gemm1_kernel<<<1563, 256, 0, stream>>>(x, aggbuf, W1l, b1l, W1r, W2l, b2l,
                                           W2r, zbufT, rbufT, flags);
    node2_kernel<<<4096, 256, 0, stream>>>(row_start, csr_src, (const uint*)zbufT,
                                           rbufT, d_out, flags);
}